// Round 1
// baseline (507.883 us; speedup 1.0000x reference)
//
#include <hip/hip_runtime.h>

// GraphSAGE 3-layer (mean aggr): N=50000 nodes, E=800000 edges, 5->64->64->32.
// Strategy: build CSR (sorted-by-dst adjacency) once per call, then each layer
// is a fused gather-mean + dual matvec, one wave (64 lanes) per node.

#define N_NODES 50000
#define N_EDGES 800000
#define IN_C 5
#define HID_C 64
#define OUT_C 32

__device__ __forceinline__ int rfl(int v) { return __builtin_amdgcn_readfirstlane(v); }

// ---------------- CSR construction ----------------

__global__ __launch_bounds__(256) void k_degree(const int* __restrict__ ei,
                                                int* __restrict__ deg) {
    int e = blockIdx.x * blockDim.x + threadIdx.x;
    if (e < N_EDGES) atomicAdd(&deg[ei[N_EDGES + e]], 1);
}

__global__ __launch_bounds__(1024) void k_scan(const int* __restrict__ deg,
                                               int* __restrict__ row_off,
                                               float* __restrict__ inv_deg) {
    __shared__ int part[1024];
    const int CH = (N_NODES + 1023) / 1024;  // 49
    int t = threadIdx.x;
    int c0 = t * CH;
    int c1 = min(N_NODES, c0 + CH);
    int s = 0;
    for (int i = c0; i < c1; ++i) s += deg[i];
    part[t] = s;
    __syncthreads();
    // Hillis-Steele inclusive scan over 1024 partials
    for (int off = 1; off < 1024; off <<= 1) {
        int v = part[t];
        int add = (t >= off) ? part[t - off] : 0;
        __syncthreads();
        part[t] = v + add;
        __syncthreads();
    }
    int ex = (t == 0) ? 0 : part[t - 1];  // exclusive prefix of this chunk
    for (int i = c0; i < c1; ++i) {
        int d = deg[i];
        row_off[i] = ex;
        ex += d;
        inv_deg[i] = 1.0f / (float)(d > 1 ? d : 1);
    }
    if (t == 1023) row_off[N_NODES] = N_EDGES;
}

__global__ __launch_bounds__(256) void k_scatter(const int* __restrict__ ei,
                                                 const int* __restrict__ row_off,
                                                 int* __restrict__ cursor,
                                                 int* __restrict__ srcs) {
    int e = blockIdx.x * blockDim.x + threadIdx.x;
    if (e < N_EDGES) {
        int d = ei[N_EDGES + e];
        int p = row_off[d] + atomicAdd(&cursor[d], 1);
        srcs[p] = ei[e];
    }
}

// ---------------- Layer 1: d_in=5 -> 64, ReLU ----------------
// One wave per node. Lanes 0..4 gather the 5 input features; all 64 lanes
// each produce one output feature via per-lane weight rows (5+5 regs).

__global__ __launch_bounds__(256) void k_layer1(
    const float* __restrict__ x, const int* __restrict__ row_off,
    const int* __restrict__ srcs, const float* __restrict__ inv_deg,
    const float* __restrict__ W1l, const float* __restrict__ b1,
    const float* __restrict__ W1r, float* __restrict__ h1) {
    const int lane = threadIdx.x & 63;
    const int wid = blockIdx.x * 4 + (threadIdx.x >> 6);
    const int nw = gridDim.x * 4;

    float wl[IN_C], wr[IN_C];
#pragma unroll
    for (int i = 0; i < IN_C; ++i) {
        wl[i] = W1l[lane * IN_C + i];
        wr[i] = W1r[lane * IN_C + i];
    }
    float bb = b1[lane];

    for (int v = wid; v < N_NODES; v += nw) {
        int beg = rfl(row_off[v]);
        int end = rfl(row_off[v + 1]);
        float sum = 0.f;
        for (int e = beg; e < end; ++e) {
            int s = srcs[e];
            if (lane < IN_C) sum += x[s * IN_C + lane];
        }
        float xv = (lane < IN_C) ? x[v * IN_C + lane] : 0.f;
        float idg = inv_deg[v];
        float acc = bb;
#pragma unroll
        for (int i = 0; i < IN_C; ++i) {
            float mi = __shfl(sum, i, 64) * idg;
            float xi = __shfl(xv, i, 64);
            acc += wl[i] * mi + wr[i] * xi;
        }
        h1[v * HID_C + lane] = fmaxf(acc, 0.f);
    }
}

// ---------------- Layers 2/3: d_in=64 -> DOUT ----------------
// One wave per node. Gather phase: lane i accumulates feature i over
// neighbors (coalesced 256B row reads). Mean + root vector go through
// per-wave LDS; matvec phase: lane j (<DOUT) holds rows Wl[j],Wr[j] in VGPRs.
// No __syncthreads: LDS traffic is wave-internal (grid-stride trip counts
// differ across waves in a block, so a block barrier would be divergent).

template <int DOUT, bool RELU>
__global__ __launch_bounds__(256) void k_layer64(
    const float* __restrict__ h, const int* __restrict__ row_off,
    const int* __restrict__ srcs, const float* __restrict__ inv_deg,
    const float* __restrict__ Wl, const float* __restrict__ bias,
    const float* __restrict__ Wr, float* __restrict__ out) {
    __shared__ __align__(16) float smem[4][128];
    const int lane = threadIdx.x & 63;
    const int wslot = threadIdx.x >> 6;
    const int wid = blockIdx.x * 4 + wslot;
    const int nw = gridDim.x * 4;

    float wl[64], wr[64];
    float bb = 0.f;
    if (lane < DOUT) {
#pragma unroll
        for (int i = 0; i < 64; i += 4) {
            float4 a = *(const float4*)(Wl + lane * 64 + i);
            wl[i] = a.x; wl[i + 1] = a.y; wl[i + 2] = a.z; wl[i + 3] = a.w;
            float4 c = *(const float4*)(Wr + lane * 64 + i);
            wr[i] = c.x; wr[i + 1] = c.y; wr[i + 2] = c.z; wr[i + 3] = c.w;
        }
        bb = bias[lane];
    }

    for (int v = wid; v < N_NODES; v += nw) {
        int beg = rfl(row_off[v]);
        int end = rfl(row_off[v + 1]);
        float sum = 0.f;
        int e = beg;
        for (; e + 4 <= end; e += 4) {
            int s0 = srcs[e + 0];
            int s1 = srcs[e + 1];
            int s2 = srcs[e + 2];
            int s3 = srcs[e + 3];
            sum += h[s0 * 64 + lane];
            sum += h[s1 * 64 + lane];
            sum += h[s2 * 64 + lane];
            sum += h[s3 * 64 + lane];
        }
        for (; e < end; ++e) {
            int s0 = srcs[e];
            sum += h[s0 * 64 + lane];
        }
        float xv = h[v * 64 + lane];
        float idg = inv_deg[v];
        smem[wslot][lane] = sum * idg;
        smem[wslot][64 + lane] = xv;
        __builtin_amdgcn_wave_barrier();
        if (lane < DOUT) {
            float acc = bb;
            const float4* mp = (const float4*)&smem[wslot][0];
#pragma unroll
            for (int q = 0; q < 16; ++q) {
                float4 m = mp[q];
                float4 xq = mp[16 + q];
                acc += wl[4 * q + 0] * m.x + wl[4 * q + 1] * m.y +
                       wl[4 * q + 2] * m.z + wl[4 * q + 3] * m.w;
                acc += wr[4 * q + 0] * xq.x + wr[4 * q + 1] * xq.y +
                       wr[4 * q + 2] * xq.z + wr[4 * q + 3] * xq.w;
            }
            out[v * DOUT + lane] = RELU ? fmaxf(acc, 0.f) : acc;
        }
        __builtin_amdgcn_wave_barrier();
    }
}

// ---------------- launch ----------------

extern "C" void kernel_launch(void* const* d_in, const int* in_sizes, int n_in,
                              void* d_out, int out_size, void* d_ws, size_t ws_size,
                              hipStream_t stream) {
    const float* x   = (const float*)d_in[0];
    const int*   ei  = (const int*)d_in[1];  // [2,E]: row0=src, row1=dst
    const float* W1l = (const float*)d_in[2];
    const float* b1  = (const float*)d_in[3];
    const float* W1r = (const float*)d_in[4];
    const float* W2l = (const float*)d_in[5];
    const float* b2  = (const float*)d_in[6];
    const float* W2r = (const float*)d_in[7];
    const float* W3l = (const float*)d_in[8];
    const float* b3  = (const float*)d_in[9];
    const float* W3r = (const float*)d_in[10];

    char* ws = (char*)d_ws;
    size_t off = 0;
    auto alloc = [&](size_t bytes) -> char* {
        char* p = ws + off;
        off += (bytes + 255) & ~(size_t)255;
        return p;
    };
    int*   deg    = (int*)alloc(N_NODES * sizeof(int));
    int*   cursor = (int*)alloc(N_NODES * sizeof(int));
    int*   rowoff = (int*)alloc((N_NODES + 1) * sizeof(int));
    float* invdeg = (float*)alloc(N_NODES * sizeof(float));
    int*   srcs   = (int*)alloc(N_EDGES * sizeof(int));
    float* h1     = (float*)alloc((size_t)N_NODES * HID_C * sizeof(float));
    float* h2     = (float*)alloc((size_t)N_NODES * HID_C * sizeof(float));

    // deg and cursor are adjacent padded regions: one memset zeroes both
    size_t degPad = (N_NODES * sizeof(int) + 255) & ~(size_t)255;
    hipMemsetAsync(deg, 0, degPad * 2, stream);

    dim3 blk(256);
    dim3 egrid((N_EDGES + 255) / 256);
    k_degree<<<egrid, blk, 0, stream>>>(ei, deg);
    k_scan<<<1, 1024, 0, stream>>>(deg, rowoff, invdeg);
    k_scatter<<<egrid, blk, 0, stream>>>(ei, rowoff, cursor, srcs);

    dim3 lgrid(1024);
    k_layer1<<<lgrid, blk, 0, stream>>>(x, rowoff, srcs, invdeg, W1l, b1, W1r, h1);
    k_layer64<HID_C, true><<<lgrid, blk, 0, stream>>>(h1, rowoff, srcs, invdeg, W2l, b2, W2r, h2);
    k_layer64<OUT_C, false><<<lgrid, blk, 0, stream>>>(h2, rowoff, srcs, invdeg, W3l, b3, W3r, (float*)d_out);
}

// Round 2
// 364.153 us; speedup vs baseline: 1.3947x; 1.3947x over previous
//
#include <hip/hip_runtime.h>

// GraphSAGE 3-layer (mean aggr): N=50000, E=800000, 5->64->64->32.
// CSR build (degree -> 3-phase parallel scan -> scatter), then per layer a
// fused gather-mean + dual matvec. Matvec weights live in LDS (transposed,
// packed float2); mean/root broadcasts via v_readlane (SGPR, no LDS pipe).

#define N_NODES 50000
#define N_EDGES 800000
#define IN_C 5
#define HID_C 64
#define OUT_C 32

#define SCAN_BLOCKS ((N_NODES + 255) / 256)  // 196

__device__ __forceinline__ int rfl(int v) { return __builtin_amdgcn_readfirstlane(v); }
__device__ __forceinline__ float lanebc(float v, int l) {
    return __int_as_float(__builtin_amdgcn_readlane(__float_as_int(v), l));
}

// ---------------- CSR construction ----------------

__global__ __launch_bounds__(256) void k_degree(const int* __restrict__ ei,
                                                int* __restrict__ deg) {
    int e = blockIdx.x * blockDim.x + threadIdx.x;
    if (e < N_EDGES) atomicAdd(&deg[ei[N_EDGES + e]], 1);
}

// Phase 1: per-block (256 nodes) degree sums
__global__ __launch_bounds__(256) void k_scan1(const int* __restrict__ deg,
                                               int* __restrict__ bsum) {
    __shared__ int red[256];
    int t = threadIdx.x;
    int idx = blockIdx.x * 256 + t;
    red[t] = (idx < N_NODES) ? deg[idx] : 0;
    __syncthreads();
#pragma unroll
    for (int o = 128; o > 0; o >>= 1) {
        if (t < o) red[t] += red[t + o];
        __syncthreads();
    }
    if (t == 0) bsum[blockIdx.x] = red[0];
}

// Phase 2: single-block exclusive scan of the 196 block sums
__global__ __launch_bounds__(256) void k_scan2(const int* __restrict__ bsum,
                                               int* __restrict__ bpre) {
    __shared__ int s[256];
    int t = threadIdx.x;
    s[t] = (t < SCAN_BLOCKS) ? bsum[t] : 0;
    __syncthreads();
#pragma unroll
    for (int o = 1; o < 256; o <<= 1) {
        int v = s[t];
        int a = (t >= o) ? s[t - o] : 0;
        __syncthreads();
        s[t] = v + a;
        __syncthreads();
    }
    bpre[t] = (t == 0) ? 0 : s[t - 1];
}

// Phase 3: local exclusive scan + block offset -> row_off, inv_deg
__global__ __launch_bounds__(256) void k_scan3(const int* __restrict__ deg,
                                               const int* __restrict__ bpre,
                                               int* __restrict__ row_off,
                                               float* __restrict__ inv_deg) {
    __shared__ int s[256];
    int t = threadIdx.x;
    int b = blockIdx.x;
    int idx = b * 256 + t;
    int d = (idx < N_NODES) ? deg[idx] : 0;
    s[t] = d;
    __syncthreads();
#pragma unroll
    for (int o = 1; o < 256; o <<= 1) {
        int v = s[t];
        int a = (t >= o) ? s[t - o] : 0;
        __syncthreads();
        s[t] = v + a;
        __syncthreads();
    }
    if (idx < N_NODES) {
        row_off[idx] = bpre[b] + (s[t] - d);  // exclusive
        inv_deg[idx] = 1.0f / (float)(d > 1 ? d : 1);
    }
    if (b == 0 && t == 0) row_off[N_NODES] = N_EDGES;
}

__global__ __launch_bounds__(256) void k_scatter(const int* __restrict__ ei,
                                                 const int* __restrict__ row_off,
                                                 int* __restrict__ cursor,
                                                 int* __restrict__ srcs) {
    int e = blockIdx.x * blockDim.x + threadIdx.x;
    if (e < N_EDGES) {
        int d = ei[N_EDGES + e];
        int p = row_off[d] + atomicAdd(&cursor[d], 1);
        srcs[p] = ei[e];
    }
}

// ---------------- Layer 1: 5 -> 64, ReLU ----------------
// One wave per node; lanes 0..4 gather the 5 input features (unroll 8 for
// MLP); per-lane weight rows (5+5 regs); broadcasts via v_readlane.

__global__ __launch_bounds__(512) void k_layer1(
    const float* __restrict__ x, const int* __restrict__ row_off,
    const int* __restrict__ srcs, const float* __restrict__ inv_deg,
    const float* __restrict__ W1l, const float* __restrict__ b1,
    const float* __restrict__ W1r, float* __restrict__ h1) {
    const int t = threadIdx.x;
    const int lane = t & 63;
    const int wid = blockIdx.x * 8 + (t >> 6);
    const int nw = gridDim.x * 8;

    float wl[IN_C], wr[IN_C];
#pragma unroll
    for (int i = 0; i < IN_C; ++i) {
        wl[i] = W1l[lane * IN_C + i];
        wr[i] = W1r[lane * IN_C + i];
    }
    float bb = b1[lane];

    for (int v = wid; v < N_NODES; v += nw) {
        int beg = rfl(row_off[v]);
        int end = rfl(row_off[v + 1]);
        float sum = 0.f;
        int e = beg;
        int e8 = beg + ((end - beg) & ~7);
        for (; e < e8; e += 8) {
            int s0 = srcs[e + 0], s1 = srcs[e + 1], s2 = srcs[e + 2], s3 = srcs[e + 3];
            int s4 = srcs[e + 4], s5 = srcs[e + 5], s6 = srcs[e + 6], s7 = srcs[e + 7];
            float a0 = (lane < IN_C) ? x[s0 * IN_C + lane] : 0.f;
            float a1 = (lane < IN_C) ? x[s1 * IN_C + lane] : 0.f;
            float a2 = (lane < IN_C) ? x[s2 * IN_C + lane] : 0.f;
            float a3 = (lane < IN_C) ? x[s3 * IN_C + lane] : 0.f;
            float a4 = (lane < IN_C) ? x[s4 * IN_C + lane] : 0.f;
            float a5 = (lane < IN_C) ? x[s5 * IN_C + lane] : 0.f;
            float a6 = (lane < IN_C) ? x[s6 * IN_C + lane] : 0.f;
            float a7 = (lane < IN_C) ? x[s7 * IN_C + lane] : 0.f;
            sum += ((a0 + a1) + (a2 + a3)) + ((a4 + a5) + (a6 + a7));
        }
        for (; e < end; ++e) {
            int s0 = srcs[e];
            if (lane < IN_C) sum += x[s0 * IN_C + lane];
        }
        float xv = (lane < IN_C) ? x[v * IN_C + lane] : 0.f;
        float summ = sum * inv_deg[v];
        float acc = bb;
#pragma unroll
        for (int i = 0; i < IN_C; ++i) {
            acc += wl[i] * lanebc(summ, i);
            acc += wr[i] * lanebc(xv, i);
        }
        h1[v * HID_C + lane] = fmaxf(acc, 0.f);
    }
}

// ---------------- Layers 2/3: 64 -> DOUT ----------------
// One wave per node. Gather: lane i sums feature i over neighbors (coalesced
// 256B rows, 8 outstanding). Matvec: weights in LDS transposed+packed
// wt[i][j]={Wl[j][i],Wr[j][i]} (2 lanes/bank = free); m_i/x_i broadcast via
// v_readlane (SGPR path, no LDS pipe, no per-wave LDS slot).

template <int DOUT, bool RELU>
__global__ __launch_bounds__(512) void k_layer64(
    const float* __restrict__ h, const int* __restrict__ row_off,
    const int* __restrict__ srcs, const float* __restrict__ inv_deg,
    const float* __restrict__ Wl, const float* __restrict__ bias,
    const float* __restrict__ Wr, float* __restrict__ out) {
    __shared__ __align__(16) float2 wt[64][DOUT];  // 32KB (DOUT=64) / 16KB (32)
    const int t = threadIdx.x;
    constexpr int LOG = (DOUT == 64) ? 6 : 5;
    for (int p = t; p < 64 * DOUT; p += 512) {
        int i = p >> LOG;
        int j = p & (DOUT - 1);
        wt[i][j] = make_float2(Wl[j * 64 + i], Wr[j * 64 + i]);
    }
    __syncthreads();  // uniform, once; waves diverge after this only

    const int lane = t & 63;
    const int jj = lane & (DOUT - 1);
    const int wid = blockIdx.x * 8 + (t >> 6);
    const int nw = gridDim.x * 8;
    float bb = (lane < DOUT) ? bias[lane] : 0.f;

    for (int v = wid; v < N_NODES; v += nw) {
        int beg = rfl(row_off[v]);
        int end = rfl(row_off[v + 1]);
        float sum = 0.f;
        int e = beg;
        int e8 = beg + ((end - beg) & ~7);
        for (; e < e8; e += 8) {
            int s0 = srcs[e + 0], s1 = srcs[e + 1], s2 = srcs[e + 2], s3 = srcs[e + 3];
            int s4 = srcs[e + 4], s5 = srcs[e + 5], s6 = srcs[e + 6], s7 = srcs[e + 7];
            float a0 = h[s0 * 64 + lane];
            float a1 = h[s1 * 64 + lane];
            float a2 = h[s2 * 64 + lane];
            float a3 = h[s3 * 64 + lane];
            float a4 = h[s4 * 64 + lane];
            float a5 = h[s5 * 64 + lane];
            float a6 = h[s6 * 64 + lane];
            float a7 = h[s7 * 64 + lane];
            sum += ((a0 + a1) + (a2 + a3)) + ((a4 + a5) + (a6 + a7));
        }
        for (; e < end; ++e) sum += h[srcs[e] * 64 + lane];

        float xv = h[v * 64 + lane];
        float summ = sum * inv_deg[v];
        float acc = bb;
#pragma unroll
        for (int i = 0; i < 64; ++i) {
            float2 w = wt[i][jj];
            acc += w.x * lanebc(summ, i);
            acc += w.y * lanebc(xv, i);
        }
        if (lane < DOUT) out[v * DOUT + lane] = RELU ? fmaxf(acc, 0.f) : acc;
    }
}

// ---------------- launch ----------------

extern "C" void kernel_launch(void* const* d_in, const int* in_sizes, int n_in,
                              void* d_out, int out_size, void* d_ws, size_t ws_size,
                              hipStream_t stream) {
    const float* x   = (const float*)d_in[0];
    const int*   ei  = (const int*)d_in[1];  // [2,E]: row0=src, row1=dst
    const float* W1l = (const float*)d_in[2];
    const float* b1  = (const float*)d_in[3];
    const float* W1r = (const float*)d_in[4];
    const float* W2l = (const float*)d_in[5];
    const float* b2  = (const float*)d_in[6];
    const float* W2r = (const float*)d_in[7];
    const float* W3l = (const float*)d_in[8];
    const float* b3  = (const float*)d_in[9];
    const float* W3r = (const float*)d_in[10];

    char* ws = (char*)d_ws;
    size_t off = 0;
    auto alloc = [&](size_t bytes) -> char* {
        char* p = ws + off;
        off += (bytes + 255) & ~(size_t)255;
        return p;
    };
    int*   deg    = (int*)alloc(N_NODES * sizeof(int));
    int*   cursor = (int*)alloc(N_NODES * sizeof(int));
    int*   rowoff = (int*)alloc((N_NODES + 1) * sizeof(int));
    float* invdeg = (float*)alloc(N_NODES * sizeof(float));
    int*   srcs   = (int*)alloc(N_EDGES * sizeof(int));
    float* h1     = (float*)alloc((size_t)N_NODES * HID_C * sizeof(float));
    float* h2     = (float*)alloc((size_t)N_NODES * HID_C * sizeof(float));
    int*   bsum   = (int*)alloc(256 * sizeof(int));
    int*   bpre   = (int*)alloc(256 * sizeof(int));

    // deg and cursor are adjacent padded regions: one memset zeroes both
    size_t degPad = (N_NODES * sizeof(int) + 255) & ~(size_t)255;
    hipMemsetAsync(deg, 0, degPad * 2, stream);

    dim3 eblk(256), egrid((N_EDGES + 255) / 256);
    k_degree<<<egrid, eblk, 0, stream>>>(ei, deg);
    k_scan1<<<dim3(SCAN_BLOCKS), dim3(256), 0, stream>>>(deg, bsum);
    k_scan2<<<dim3(1), dim3(256), 0, stream>>>(bsum, bpre);
    k_scan3<<<dim3(SCAN_BLOCKS), dim3(256), 0, stream>>>(deg, bpre, rowoff, invdeg);
    k_scatter<<<egrid, eblk, 0, stream>>>(ei, rowoff, cursor, srcs);

    dim3 lblk(512), lgrid(1024);
    k_layer1<<<lgrid, lblk, 0, stream>>>(x, rowoff, srcs, invdeg, W1l, b1, W1r, h1);
    k_layer64<HID_C, true><<<lgrid, lblk, 0, stream>>>(h1, rowoff, srcs, invdeg, W2l, b2, W2r, h2);
    k_layer64<OUT_C, false><<<lgrid, lblk, 0, stream>>>(h2, rowoff, srcs, invdeg, W3l, b3, W3r, (float*)d_out);
}

// Round 3
// 305.331 us; speedup vs baseline: 1.6634x; 1.1926x over previous
//
#include <hip/hip_runtime.h>

// GraphSAGE 3-layer (mean aggr): N=50000, E=800000, 5->64->64->32.
// Round 3: decouple gather from transform.
//   CSR build -> fused layer1 (K=10 matvec) -> per fat layer:
//   k_gather (lean, full-occupancy, writes [mean||x] as bf16 hi/lo split)
//   k_gemm   (MFMA 16x16x32 bf16, 3-product split = fp32-grade accuracy)

#define N_NODES 50000
#define N_EDGES 800000
#define IN_C 5
#define HID_C 64
#define OUT_C 32
#define SCAN_BLOCKS ((N_NODES + 255) / 256)  // 196

typedef __attribute__((ext_vector_type(8))) short bf16x8;   // 8 bf16 = 4 VGPRs
typedef __attribute__((ext_vector_type(4))) float f32x4;    // 4 fp32 acc

__device__ __forceinline__ int rfl(int v) { return __builtin_amdgcn_readfirstlane(v); }
__device__ __forceinline__ float lanebc(float v, int l) {
    return __int_as_float(__builtin_amdgcn_readlane(__float_as_int(v), l));
}
__device__ __forceinline__ unsigned short f2bf(float f) {  // RNE
    unsigned u = __float_as_uint(f);
    return (unsigned short)((u + 0x7fffu + ((u >> 16) & 1u)) >> 16);
}
__device__ __forceinline__ float bf2f(unsigned short b) {
    return __uint_as_float(((unsigned)b) << 16);
}

// ---------------- CSR construction ----------------

__global__ __launch_bounds__(256) void k_degree(const int* __restrict__ ei,
                                                int* __restrict__ deg) {
    int e = blockIdx.x * blockDim.x + threadIdx.x;
    if (e < N_EDGES) atomicAdd(&deg[ei[N_EDGES + e]], 1);
}

__global__ __launch_bounds__(256) void k_scan1(const int* __restrict__ deg,
                                               int* __restrict__ bsum) {
    __shared__ int red[256];
    int t = threadIdx.x;
    int idx = blockIdx.x * 256 + t;
    red[t] = (idx < N_NODES) ? deg[idx] : 0;
    __syncthreads();
#pragma unroll
    for (int o = 128; o > 0; o >>= 1) {
        if (t < o) red[t] += red[t + o];
        __syncthreads();
    }
    if (t == 0) bsum[blockIdx.x] = red[0];
}

__global__ __launch_bounds__(256) void k_scan2(const int* __restrict__ bsum,
                                               int* __restrict__ bpre) {
    __shared__ int s[256];
    int t = threadIdx.x;
    s[t] = (t < SCAN_BLOCKS) ? bsum[t] : 0;
    __syncthreads();
#pragma unroll
    for (int o = 1; o < 256; o <<= 1) {
        int v = s[t];
        int a = (t >= o) ? s[t - o] : 0;
        __syncthreads();
        s[t] = v + a;
        __syncthreads();
    }
    bpre[t] = (t == 0) ? 0 : s[t - 1];
}

__global__ __launch_bounds__(256) void k_scan3(const int* __restrict__ deg,
                                               const int* __restrict__ bpre,
                                               int* __restrict__ row_off,
                                               float* __restrict__ inv_deg) {
    __shared__ int s[256];
    int t = threadIdx.x;
    int b = blockIdx.x;
    int idx = b * 256 + t;
    int d = (idx < N_NODES) ? deg[idx] : 0;
    s[t] = d;
    __syncthreads();
#pragma unroll
    for (int o = 1; o < 256; o <<= 1) {
        int v = s[t];
        int a = (t >= o) ? s[t - o] : 0;
        __syncthreads();
        s[t] = v + a;
        __syncthreads();
    }
    if (idx < N_NODES) {
        row_off[idx] = bpre[b] + (s[t] - d);
        inv_deg[idx] = 1.0f / (float)(d > 1 ? d : 1);
    }
    if (b == 0 && t == 0) row_off[N_NODES] = N_EDGES;
}

__global__ __launch_bounds__(256) void k_scatter(const int* __restrict__ ei,
                                                 const int* __restrict__ row_off,
                                                 int* __restrict__ cursor,
                                                 int* __restrict__ srcs) {
    int e = blockIdx.x * blockDim.x + threadIdx.x;
    if (e < N_EDGES) {
        int d = ei[N_EDGES + e];
        int p = row_off[d] + atomicAdd(&cursor[d], 1);
        srcs[p] = ei[e];
    }
}

// ---------------- weight prep: Wcat = [Wl | Wr], bf16 hi/lo split ----------------

__global__ __launch_bounds__(256) void k_prep(
    const float* __restrict__ W2l, const float* __restrict__ W2r,
    const float* __restrict__ W3l, const float* __restrict__ W3r,
    unsigned short* __restrict__ W2hi, unsigned short* __restrict__ W2lo,
    unsigned short* __restrict__ W3hi, unsigned short* __restrict__ W3lo) {
    int t = blockIdx.x * 256 + threadIdx.x;
    int stride = gridDim.x * 256;
    for (int p = t; p < 64 * 128; p += stride) {
        int j = p >> 7, k = p & 127;
        float w = (k < 64) ? W2l[j * 64 + k] : W2r[j * 64 + (k - 64)];
        unsigned short h = f2bf(w);
        W2hi[p] = h;
        W2lo[p] = f2bf(w - bf2f(h));
    }
    for (int p = t; p < 32 * 128; p += stride) {
        int j = p >> 7, k = p & 127;
        float w = (k < 64) ? W3l[j * 64 + k] : W3r[j * 64 + (k - 64)];
        unsigned short h = f2bf(w);
        W3hi[p] = h;
        W3lo[p] = f2bf(w - bf2f(h));
    }
}

// ---------------- Layer 1: 5 -> 64 fused, ReLU ----------------

__global__ __launch_bounds__(512) void k_layer1(
    const float* __restrict__ x, const int* __restrict__ row_off,
    const int* __restrict__ srcs, const float* __restrict__ inv_deg,
    const float* __restrict__ W1l, const float* __restrict__ b1,
    const float* __restrict__ W1r, float* __restrict__ h1) {
    const int t = threadIdx.x;
    const int lane = t & 63;
    const int v = blockIdx.x * 8 + (t >> 6);
    if (v >= N_NODES) return;

    float wl[IN_C], wr[IN_C];
#pragma unroll
    for (int i = 0; i < IN_C; ++i) {
        wl[i] = W1l[lane * IN_C + i];
        wr[i] = W1r[lane * IN_C + i];
    }
    float bb = b1[lane];

    int beg = rfl(row_off[v]);
    int end = rfl(row_off[v + 1]);
    float sum = 0.f;
    int e = beg;
    int e8 = beg + ((end - beg) & ~7);
    for (; e < e8; e += 8) {
        int s0 = srcs[e + 0], s1 = srcs[e + 1], s2 = srcs[e + 2], s3 = srcs[e + 3];
        int s4 = srcs[e + 4], s5 = srcs[e + 5], s6 = srcs[e + 6], s7 = srcs[e + 7];
        float a0 = (lane < IN_C) ? x[s0 * IN_C + lane] : 0.f;
        float a1 = (lane < IN_C) ? x[s1 * IN_C + lane] : 0.f;
        float a2 = (lane < IN_C) ? x[s2 * IN_C + lane] : 0.f;
        float a3 = (lane < IN_C) ? x[s3 * IN_C + lane] : 0.f;
        float a4 = (lane < IN_C) ? x[s4 * IN_C + lane] : 0.f;
        float a5 = (lane < IN_C) ? x[s5 * IN_C + lane] : 0.f;
        float a6 = (lane < IN_C) ? x[s6 * IN_C + lane] : 0.f;
        float a7 = (lane < IN_C) ? x[s7 * IN_C + lane] : 0.f;
        sum += ((a0 + a1) + (a2 + a3)) + ((a4 + a5) + (a6 + a7));
    }
    for (; e < end; ++e) {
        int s0 = srcs[e];
        if (lane < IN_C) sum += x[s0 * IN_C + lane];
    }
    float xv = (lane < IN_C) ? x[v * IN_C + lane] : 0.f;
    float summ = sum * inv_deg[v];
    float acc = bb;
#pragma unroll
    for (int i = 0; i < IN_C; ++i) {
        acc += wl[i] * lanebc(summ, i);
        acc += wr[i] * lanebc(xv, i);
    }
    h1[v * HID_C + lane] = fmaxf(acc, 0.f);
}

// ---------------- gather: h[N,64] fp32 -> A[N,128] bf16 hi/lo ([mean || x]) ----
// One lean wave per node: no LDS, low VGPR -> full occupancy for latency hiding.

__global__ __launch_bounds__(256) void k_gather(
    const float* __restrict__ h, const int* __restrict__ row_off,
    const int* __restrict__ srcs, const float* __restrict__ inv_deg,
    unsigned short* __restrict__ Ahi, unsigned short* __restrict__ Alo) {
    const int lane = threadIdx.x & 63;
    const int v = blockIdx.x * 4 + (threadIdx.x >> 6);
    if (v >= N_NODES) return;

    int beg = rfl(row_off[v]);
    int end = rfl(row_off[v + 1]);
    float sum = 0.f;
    int e = beg;
    int e8 = beg + ((end - beg) & ~7);
    for (; e < e8; e += 8) {
        int s0 = srcs[e + 0], s1 = srcs[e + 1], s2 = srcs[e + 2], s3 = srcs[e + 3];
        int s4 = srcs[e + 4], s5 = srcs[e + 5], s6 = srcs[e + 6], s7 = srcs[e + 7];
        float a0 = h[s0 * 64 + lane];
        float a1 = h[s1 * 64 + lane];
        float a2 = h[s2 * 64 + lane];
        float a3 = h[s3 * 64 + lane];
        float a4 = h[s4 * 64 + lane];
        float a5 = h[s5 * 64 + lane];
        float a6 = h[s6 * 64 + lane];
        float a7 = h[s7 * 64 + lane];
        sum += ((a0 + a1) + (a2 + a3)) + ((a4 + a5) + (a6 + a7));
    }
    for (; e < end; ++e) sum += h[srcs[e] * 64 + lane];

    float xv = h[v * 64 + lane];
    float m = sum * inv_deg[v];
    unsigned short mh = f2bf(m);
    unsigned short ml = f2bf(m - bf2f(mh));
    unsigned short xh = f2bf(xv);
    unsigned short xl = f2bf(xv - bf2f(xh));
    size_t base = (size_t)v * 128;
    Ahi[base + lane] = mh;
    Ahi[base + 64 + lane] = xh;
    Alo[base + lane] = ml;
    Alo[base + 64 + lane] = xl;
}

// ---------------- GEMM: out[N,DOUT] = A[N,128] @ Wcat[DOUT,128]^T + b -------
// MFMA 16x16x32 bf16, split product hh + hl + lh (fp32-grade accuracy).
// One wave per 16-node tile; A-frag: lane holds A[m=lane&15][k=quad*8+j];
// B-frag: lane holds Wcat[n=lane&15][k=quad*8+j]; D: col=lane&15, row=quad*4+g.

template <int DOUT, bool RELU>
__global__ __launch_bounds__(256) void k_gemm(
    const unsigned short* __restrict__ Ahi, const unsigned short* __restrict__ Alo,
    const unsigned short* __restrict__ Whi, const unsigned short* __restrict__ Wlo,
    const float* __restrict__ bias, float* __restrict__ out) {
    constexpr int NT = DOUT / 16;
    const int lane = threadIdx.x & 63;
    const int tile = blockIdx.x * 4 + (threadIdx.x >> 6);
    if (tile >= N_NODES / 16) return;
    const int node0 = tile * 16;
    const int r = lane & 15;
    const int quad = lane >> 4;

    f32x4 acc[NT];
#pragma unroll
    for (int n = 0; n < NT; ++n) acc[n] = (f32x4){0.f, 0.f, 0.f, 0.f};

    const size_t abase = ((size_t)(node0 + r)) * 128 + quad * 8;
#pragma unroll
    for (int ks = 0; ks < 4; ++ks) {
        bf16x8 ah = *(const bf16x8*)(Ahi + abase + ks * 32);
        bf16x8 al = *(const bf16x8*)(Alo + abase + ks * 32);
#pragma unroll
        for (int n = 0; n < NT; ++n) {
            const size_t wbase = ((size_t)(n * 16 + r)) * 128 + ks * 32 + quad * 8;
            bf16x8 bh = *(const bf16x8*)(Whi + wbase);
            bf16x8 bl = *(const bf16x8*)(Wlo + wbase);
            acc[n] = __builtin_amdgcn_mfma_f32_16x16x32_bf16(ah, bh, acc[n], 0, 0, 0);
            acc[n] = __builtin_amdgcn_mfma_f32_16x16x32_bf16(ah, bl, acc[n], 0, 0, 0);
            acc[n] = __builtin_amdgcn_mfma_f32_16x16x32_bf16(al, bh, acc[n], 0, 0, 0);
        }
    }
#pragma unroll
    for (int n = 0; n < NT; ++n) {
        float bv = bias[n * 16 + r];
#pragma unroll
        for (int g = 0; g < 4; ++g) {
            int m = quad * 4 + g;
            float vacc = acc[n][g] + bv;
            if (RELU) vacc = fmaxf(vacc, 0.f);
            out[(size_t)(node0 + m) * DOUT + n * 16 + r] = vacc;
        }
    }
}

// ---------------- launch ----------------

extern "C" void kernel_launch(void* const* d_in, const int* in_sizes, int n_in,
                              void* d_out, int out_size, void* d_ws, size_t ws_size,
                              hipStream_t stream) {
    const float* x   = (const float*)d_in[0];
    const int*   ei  = (const int*)d_in[1];  // [2,E]: row0=src, row1=dst
    const float* W1l = (const float*)d_in[2];
    const float* b1  = (const float*)d_in[3];
    const float* W1r = (const float*)d_in[4];
    const float* W2l = (const float*)d_in[5];
    const float* b2  = (const float*)d_in[6];
    const float* W2r = (const float*)d_in[7];
    const float* W3l = (const float*)d_in[8];
    const float* b3  = (const float*)d_in[9];
    const float* W3r = (const float*)d_in[10];

    char* ws = (char*)d_ws;
    size_t off = 0;
    auto alloc = [&](size_t bytes) -> char* {
        char* p = ws + off;
        off += (bytes + 255) & ~(size_t)255;
        return p;
    };
    int*   deg    = (int*)alloc(N_NODES * sizeof(int));
    int*   cursor = (int*)alloc(N_NODES * sizeof(int));
    int*   rowoff = (int*)alloc((N_NODES + 1) * sizeof(int));
    float* invdeg = (float*)alloc(N_NODES * sizeof(float));
    int*   srcs   = (int*)alloc(N_EDGES * sizeof(int));
    float* h1     = (float*)alloc((size_t)N_NODES * HID_C * sizeof(float));  // h2 aliases h1
    unsigned short* Ahi = (unsigned short*)alloc((size_t)N_NODES * 128 * 2);
    unsigned short* Alo = (unsigned short*)alloc((size_t)N_NODES * 128 * 2);
    unsigned short* W2hi = (unsigned short*)alloc(64 * 128 * 2);
    unsigned short* W2lo = (unsigned short*)alloc(64 * 128 * 2);
    unsigned short* W3hi = (unsigned short*)alloc(32 * 128 * 2);
    unsigned short* W3lo = (unsigned short*)alloc(32 * 128 * 2);
    int*   bsum   = (int*)alloc(256 * sizeof(int));
    int*   bpre   = (int*)alloc(256 * sizeof(int));
    float* h2 = h1;  // h1 dead after first gather; reuse

    size_t degPad = (N_NODES * sizeof(int) + 255) & ~(size_t)255;
    hipMemsetAsync(deg, 0, degPad * 2, stream);  // deg + cursor

    dim3 eblk(256), egrid((N_EDGES + 255) / 256);
    k_prep<<<dim3(48), dim3(256), 0, stream>>>(W2l, W2r, W3l, W3r, W2hi, W2lo, W3hi, W3lo);
    k_degree<<<egrid, eblk, 0, stream>>>(ei, deg);
    k_scan1<<<dim3(SCAN_BLOCKS), dim3(256), 0, stream>>>(deg, bsum);
    k_scan2<<<dim3(1), dim3(256), 0, stream>>>(bsum, bpre);
    k_scan3<<<dim3(SCAN_BLOCKS), dim3(256), 0, stream>>>(deg, bpre, rowoff, invdeg);
    k_scatter<<<egrid, eblk, 0, stream>>>(ei, rowoff, cursor, srcs);

    // layer 1 (fused): x -> h1
    k_layer1<<<dim3((N_NODES + 7) / 8), dim3(512), 0, stream>>>(
        x, rowoff, srcs, invdeg, W1l, b1, W1r, h1);

    // layer 2: gather(h1) -> A; gemm -> h2 (ReLU)
    k_gather<<<dim3((N_NODES + 3) / 4), dim3(256), 0, stream>>>(
        h1, rowoff, srcs, invdeg, Ahi, Alo);
    k_gemm<HID_C, true><<<dim3((N_NODES / 16 + 3) / 4), dim3(256), 0, stream>>>(
        Ahi, Alo, W2hi, W2lo, b2, h2);

    // layer 3: gather(h2) -> A; gemm -> out
    k_gather<<<dim3((N_NODES + 3) / 4), dim3(256), 0, stream>>>(
        h2, rowoff, srcs, invdeg, Ahi, Alo);
    k_gemm<OUT_C, false><<<dim3((N_NODES / 16 + 3) / 4), dim3(256), 0, stream>>>(
        Ahi, Alo, W3hi, W3lo, b3, (float*)d_out);
}

// Round 4
// 245.574 us; speedup vs baseline: 2.0681x; 1.2433x over previous
//
#include <hip/hip_runtime.h>

// GraphSAGE 3-layer (mean aggr): N=50000, E=800000, 5->64->64->32.
// Round 4: CSR build via bucketed counting sort (no 17x-amplified random
// scatter): k_bucket (196 coarse buckets, LDS histogram + range-reserve,
// packed (dstlow<<16|src) entries) -> k_bscan -> k_bsort (per-bucket LDS
// counting sort; emits row_off, inv_deg, coalesced srcs).
// Then: fused layer1 (K=10 matvec); per fat layer k_gather (lean, writes
// [mean||x] bf16 hi/lo split) + k_gemm (MFMA 16x16x32 bf16, 3-product split).

#define N_NODES 50000
#define N_EDGES 800000
#define IN_C 5
#define HID_C 64
#define OUT_C 32

#define NB 196        // buckets of 256 nodes (dst >> 8)
#define BCAP 6144     // per-bucket region capacity (mean 4082, sigma ~64)
#define BWG 256       // k_bucket workgroups
#define BCH (N_EDGES / BWG)  // 3125 edges per workgroup

typedef __attribute__((ext_vector_type(8))) short bf16x8;   // 8 bf16 = 4 VGPRs
typedef __attribute__((ext_vector_type(4))) float f32x4;    // 4 fp32 acc

__device__ __forceinline__ int rfl(int v) { return __builtin_amdgcn_readfirstlane(v); }
__device__ __forceinline__ float lanebc(float v, int l) {
    return __int_as_float(__builtin_amdgcn_readlane(__float_as_int(v), l));
}
__device__ __forceinline__ unsigned short f2bf(float f) {  // RNE
    unsigned u = __float_as_uint(f);
    return (unsigned short)((u + 0x7fffu + ((u >> 16) & 1u)) >> 16);
}
__device__ __forceinline__ float bf2f(unsigned short b) {
    return __uint_as_float(((unsigned)b) << 16);
}

// ---------------- CSR build: bucketed counting sort ----------------

// Phase A: bin edges into NB coarse buckets. Per-wg LDS histogram, one global
// atomicAdd per (wg,bucket) to reserve a contiguous range, then direct packed
// writes into the reserved range (XCD-local, bursty -> low write amp).
__global__ __launch_bounds__(256) void k_bucket(const int* __restrict__ ei,
                                                int* __restrict__ gcur,
                                                int* __restrict__ ebuf) {
    __shared__ int hist[NB];
    __shared__ int base[NB];
    const int t = threadIdx.x;
    const int c0 = blockIdx.x * BCH;
    const int c1 = c0 + BCH;
    if (t < NB) hist[t] = 0;
    __syncthreads();
    for (int e = c0 + t; e < c1; e += 256) {
        int d = ei[N_EDGES + e];
        atomicAdd(&hist[d >> 8], 1);
    }
    __syncthreads();
    if (t < NB) {
        base[t] = atomicAdd(&gcur[t], hist[t]);
        hist[t] = 0;  // reuse as local cursor
    }
    __syncthreads();
    for (int e = c0 + t; e < c1; e += 256) {
        int d = ei[N_EDGES + e];
        int s = ei[e];
        int b = d >> 8;
        int p = base[b] + atomicAdd(&hist[b], 1);
        if (p < BCAP) ebuf[b * BCAP + p] = ((d & 255) << 16) | s;
    }
}

// Phase B: exclusive scan of bucket counts -> global bases; row_off[N]=E.
__global__ __launch_bounds__(256) void k_bscan(const int* __restrict__ gcur,
                                               int* __restrict__ bbase,
                                               int* __restrict__ row_off) {
    __shared__ int s[256];
    int t = threadIdx.x;
    s[t] = (t < NB) ? gcur[t] : 0;
    __syncthreads();
#pragma unroll
    for (int o = 1; o < 256; o <<= 1) {
        int v = s[t];
        int a = (t >= o) ? s[t - o] : 0;
        __syncthreads();
        s[t] = v + a;
        __syncthreads();
    }
    if (t < NB) bbase[t] = (t == 0) ? 0 : s[t - 1];
    if (t == 0) row_off[N_NODES] = N_EDGES;
}

// Phase C: per-bucket counting sort by dstlow. Emits row_off + inv_deg for
// the bucket's 256 nodes and fully-coalesced srcs via LDS staging.
__global__ __launch_bounds__(256) void k_bsort(const int* __restrict__ gcur,
                                               const int* __restrict__ bbase,
                                               const int* __restrict__ ebuf,
                                               int* __restrict__ row_off,
                                               float* __restrict__ inv_deg,
                                               int* __restrict__ srcs) {
    __shared__ int cnt[256];
    __shared__ int loff[256];
    __shared__ int cur[256];
    __shared__ int stage[BCAP];
    const int t = threadIdx.x;
    const int b = blockIdx.x;
    const int n = gcur[b] < BCAP ? gcur[b] : BCAP;
    const int base = bbase[b];
    const int node0 = b << 8;
    const int* eb = ebuf + b * BCAP;

    cnt[t] = 0;
    __syncthreads();
    for (int i = t; i < n; i += 256) atomicAdd(&cnt[(eb[i] >> 16) & 255], 1);
    __syncthreads();
    loff[t] = cnt[t];
    __syncthreads();
#pragma unroll
    for (int o = 1; o < 256; o <<= 1) {
        int v = loff[t];
        int a = (t >= o) ? loff[t - o] : 0;
        __syncthreads();
        loff[t] = v + a;
        __syncthreads();
    }
    int ex = loff[t] - cnt[t];  // exclusive
    cur[t] = ex;
    int node = node0 + t;
    if (node < N_NODES) {
        row_off[node] = base + ex;
        int d = cnt[t];
        inv_deg[node] = 1.0f / (float)(d > 1 ? d : 1);
    }
    __syncthreads();
    for (int i = t; i < n; i += 256) {
        int v = eb[i];
        int p = atomicAdd(&cur[(v >> 16) & 255], 1);
        stage[p] = v & 0xFFFF;
    }
    __syncthreads();
    for (int i = t; i < n; i += 256) srcs[base + i] = stage[i];
}

// ---------------- weight prep: Wcat = [Wl | Wr], bf16 hi/lo split ----------

__global__ __launch_bounds__(256) void k_prep(
    const float* __restrict__ W2l, const float* __restrict__ W2r,
    const float* __restrict__ W3l, const float* __restrict__ W3r,
    unsigned short* __restrict__ W2hi, unsigned short* __restrict__ W2lo,
    unsigned short* __restrict__ W3hi, unsigned short* __restrict__ W3lo) {
    int t = blockIdx.x * 256 + threadIdx.x;
    int stride = gridDim.x * 256;
    for (int p = t; p < 64 * 128; p += stride) {
        int j = p >> 7, k = p & 127;
        float w = (k < 64) ? W2l[j * 64 + k] : W2r[j * 64 + (k - 64)];
        unsigned short h = f2bf(w);
        W2hi[p] = h;
        W2lo[p] = f2bf(w - bf2f(h));
    }
    for (int p = t; p < 32 * 128; p += stride) {
        int j = p >> 7, k = p & 127;
        float w = (k < 64) ? W3l[j * 64 + k] : W3r[j * 64 + (k - 64)];
        unsigned short h = f2bf(w);
        W3hi[p] = h;
        W3lo[p] = f2bf(w - bf2f(h));
    }
}

// ---------------- Layer 1: 5 -> 64 fused, ReLU ----------------

__global__ __launch_bounds__(512) void k_layer1(
    const float* __restrict__ x, const int* __restrict__ row_off,
    const int* __restrict__ srcs, const float* __restrict__ inv_deg,
    const float* __restrict__ W1l, const float* __restrict__ b1,
    const float* __restrict__ W1r, float* __restrict__ h1) {
    const int t = threadIdx.x;
    const int lane = t & 63;
    const int v = blockIdx.x * 8 + (t >> 6);
    if (v >= N_NODES) return;

    float wl[IN_C], wr[IN_C];
#pragma unroll
    for (int i = 0; i < IN_C; ++i) {
        wl[i] = W1l[lane * IN_C + i];
        wr[i] = W1r[lane * IN_C + i];
    }
    float bb = b1[lane];

    int beg = rfl(row_off[v]);
    int end = rfl(row_off[v + 1]);
    float sum = 0.f;
    int e = beg;
    int e8 = beg + ((end - beg) & ~7);
    for (; e < e8; e += 8) {
        int s0 = srcs[e + 0], s1 = srcs[e + 1], s2 = srcs[e + 2], s3 = srcs[e + 3];
        int s4 = srcs[e + 4], s5 = srcs[e + 5], s6 = srcs[e + 6], s7 = srcs[e + 7];
        float a0 = (lane < IN_C) ? x[s0 * IN_C + lane] : 0.f;
        float a1 = (lane < IN_C) ? x[s1 * IN_C + lane] : 0.f;
        float a2 = (lane < IN_C) ? x[s2 * IN_C + lane] : 0.f;
        float a3 = (lane < IN_C) ? x[s3 * IN_C + lane] : 0.f;
        float a4 = (lane < IN_C) ? x[s4 * IN_C + lane] : 0.f;
        float a5 = (lane < IN_C) ? x[s5 * IN_C + lane] : 0.f;
        float a6 = (lane < IN_C) ? x[s6 * IN_C + lane] : 0.f;
        float a7 = (lane < IN_C) ? x[s7 * IN_C + lane] : 0.f;
        sum += ((a0 + a1) + (a2 + a3)) + ((a4 + a5) + (a6 + a7));
    }
    for (; e < end; ++e) {
        int s0 = srcs[e];
        if (lane < IN_C) sum += x[s0 * IN_C + lane];
    }
    float xv = (lane < IN_C) ? x[v * IN_C + lane] : 0.f;
    float summ = sum * inv_deg[v];
    float acc = bb;
#pragma unroll
    for (int i = 0; i < IN_C; ++i) {
        acc += wl[i] * lanebc(summ, i);
        acc += wr[i] * lanebc(xv, i);
    }
    h1[v * HID_C + lane] = fmaxf(acc, 0.f);
}

// ---------------- gather: h[N,64] fp32 -> A[N,128] bf16 hi/lo ([mean || x]) --

__global__ __launch_bounds__(256) void k_gather(
    const float* __restrict__ h, const int* __restrict__ row_off,
    const int* __restrict__ srcs, const float* __restrict__ inv_deg,
    unsigned short* __restrict__ Ahi, unsigned short* __restrict__ Alo) {
    const int lane = threadIdx.x & 63;
    const int v = blockIdx.x * 4 + (threadIdx.x >> 6);
    if (v >= N_NODES) return;

    int beg = rfl(row_off[v]);
    int end = rfl(row_off[v + 1]);
    float sum = 0.f;
    int e = beg;
    int e8 = beg + ((end - beg) & ~7);
    for (; e < e8; e += 8) {
        int s0 = srcs[e + 0], s1 = srcs[e + 1], s2 = srcs[e + 2], s3 = srcs[e + 3];
        int s4 = srcs[e + 4], s5 = srcs[e + 5], s6 = srcs[e + 6], s7 = srcs[e + 7];
        float a0 = h[s0 * 64 + lane];
        float a1 = h[s1 * 64 + lane];
        float a2 = h[s2 * 64 + lane];
        float a3 = h[s3 * 64 + lane];
        float a4 = h[s4 * 64 + lane];
        float a5 = h[s5 * 64 + lane];
        float a6 = h[s6 * 64 + lane];
        float a7 = h[s7 * 64 + lane];
        sum += ((a0 + a1) + (a2 + a3)) + ((a4 + a5) + (a6 + a7));
    }
    for (; e < end; ++e) sum += h[srcs[e] * 64 + lane];

    float xv = h[v * 64 + lane];
    float m = sum * inv_deg[v];
    unsigned short mh = f2bf(m);
    unsigned short ml = f2bf(m - bf2f(mh));
    unsigned short xh = f2bf(xv);
    unsigned short xl = f2bf(xv - bf2f(xh));
    size_t base = (size_t)v * 128;
    Ahi[base + lane] = mh;
    Ahi[base + 64 + lane] = xh;
    Alo[base + lane] = ml;
    Alo[base + 64 + lane] = xl;
}

// ---------------- GEMM: out[N,DOUT] = A[N,128] @ Wcat[DOUT,128]^T + b -------

template <int DOUT, bool RELU>
__global__ __launch_bounds__(256) void k_gemm(
    const unsigned short* __restrict__ Ahi, const unsigned short* __restrict__ Alo,
    const unsigned short* __restrict__ Whi, const unsigned short* __restrict__ Wlo,
    const float* __restrict__ bias, float* __restrict__ out) {
    constexpr int NT = DOUT / 16;
    const int lane = threadIdx.x & 63;
    const int tile = blockIdx.x * 4 + (threadIdx.x >> 6);
    if (tile >= N_NODES / 16) return;
    const int node0 = tile * 16;
    const int r = lane & 15;
    const int quad = lane >> 4;

    f32x4 acc[NT];
#pragma unroll
    for (int n = 0; n < NT; ++n) acc[n] = (f32x4){0.f, 0.f, 0.f, 0.f};

    const size_t abase = ((size_t)(node0 + r)) * 128 + quad * 8;
#pragma unroll
    for (int ks = 0; ks < 4; ++ks) {
        bf16x8 ah = *(const bf16x8*)(Ahi + abase + ks * 32);
        bf16x8 al = *(const bf16x8*)(Alo + abase + ks * 32);
#pragma unroll
        for (int n = 0; n < NT; ++n) {
            const size_t wbase = ((size_t)(n * 16 + r)) * 128 + ks * 32 + quad * 8;
            bf16x8 bh = *(const bf16x8*)(Whi + wbase);
            bf16x8 bl = *(const bf16x8*)(Wlo + wbase);
            acc[n] = __builtin_amdgcn_mfma_f32_16x16x32_bf16(ah, bh, acc[n], 0, 0, 0);
            acc[n] = __builtin_amdgcn_mfma_f32_16x16x32_bf16(ah, bl, acc[n], 0, 0, 0);
            acc[n] = __builtin_amdgcn_mfma_f32_16x16x32_bf16(al, bh, acc[n], 0, 0, 0);
        }
    }
#pragma unroll
    for (int n = 0; n < NT; ++n) {
        float bv = bias[n * 16 + r];
#pragma unroll
        for (int g = 0; g < 4; ++g) {
            int m = quad * 4 + g;
            float vacc = acc[n][g] + bv;
            if (RELU) vacc = fmaxf(vacc, 0.f);
            out[(size_t)(node0 + m) * DOUT + n * 16 + r] = vacc;
        }
    }
}

// ---------------- launch ----------------

extern "C" void kernel_launch(void* const* d_in, const int* in_sizes, int n_in,
                              void* d_out, int out_size, void* d_ws, size_t ws_size,
                              hipStream_t stream) {
    const float* x   = (const float*)d_in[0];
    const int*   ei  = (const int*)d_in[1];  // [2,E]: row0=src, row1=dst
    const float* W1l = (const float*)d_in[2];
    const float* b1  = (const float*)d_in[3];
    const float* W1r = (const float*)d_in[4];
    const float* W2l = (const float*)d_in[5];
    const float* b2  = (const float*)d_in[6];
    const float* W2r = (const float*)d_in[7];
    const float* W3l = (const float*)d_in[8];
    const float* b3  = (const float*)d_in[9];
    const float* W3r = (const float*)d_in[10];

    char* ws = (char*)d_ws;
    size_t off = 0;
    auto alloc = [&](size_t bytes) -> char* {
        char* p = ws + off;
        off += (bytes + 255) & ~(size_t)255;
        return p;
    };
    int*   gcur   = (int*)alloc(NB * sizeof(int));
    int*   bbase  = (int*)alloc(NB * sizeof(int));
    int*   rowoff = (int*)alloc((N_NODES + 1) * sizeof(int));
    float* invdeg = (float*)alloc(N_NODES * sizeof(float));
    int*   srcs   = (int*)alloc(N_EDGES * sizeof(int));
    float* h1     = (float*)alloc((size_t)N_NODES * HID_C * sizeof(float));
    unsigned short* Ahi = (unsigned short*)alloc((size_t)N_NODES * 128 * 2);
    unsigned short* Alo = (unsigned short*)alloc((size_t)N_NODES * 128 * 2);
    unsigned short* W2hi = (unsigned short*)alloc(64 * 128 * 2);
    unsigned short* W2lo = (unsigned short*)alloc(64 * 128 * 2);
    unsigned short* W3hi = (unsigned short*)alloc(32 * 128 * 2);
    unsigned short* W3lo = (unsigned short*)alloc(32 * 128 * 2);
    float* h2 = h1;                 // h1 dead after gather(layer2)
    int*   ebuf = (int*)Ahi;        // ebuf (4.8 MB) dead before Ahi is written

    hipMemsetAsync(gcur, 0, NB * sizeof(int), stream);

    // CSR build
    k_prep<<<dim3(48), dim3(256), 0, stream>>>(W2l, W2r, W3l, W3r, W2hi, W2lo, W3hi, W3lo);
    k_bucket<<<dim3(BWG), dim3(256), 0, stream>>>(ei, gcur, ebuf);
    k_bscan<<<dim3(1), dim3(256), 0, stream>>>(gcur, bbase, rowoff);
    k_bsort<<<dim3(NB), dim3(256), 0, stream>>>(gcur, bbase, ebuf, rowoff, invdeg, srcs);

    // layer 1 (fused): x -> h1
    k_layer1<<<dim3((N_NODES + 7) / 8), dim3(512), 0, stream>>>(
        x, rowoff, srcs, invdeg, W1l, b1, W1r, h1);

    // layer 2: gather(h1) -> A; gemm -> h2 (ReLU)
    k_gather<<<dim3((N_NODES + 3) / 4), dim3(256), 0, stream>>>(
        h1, rowoff, srcs, invdeg, Ahi, Alo);
    k_gemm<HID_C, true><<<dim3((N_NODES / 16 + 3) / 4), dim3(256), 0, stream>>>(
        Ahi, Alo, W2hi, W2lo, b2, h2);

    // layer 3: gather(h2) -> A; gemm -> out
    k_gather<<<dim3((N_NODES + 3) / 4), dim3(256), 0, stream>>>(
        h2, rowoff, srcs, invdeg, Ahi, Alo);
    k_gemm<OUT_C, false><<<dim3((N_NODES / 16 + 3) / 4), dim3(256), 0, stream>>>(
        Ahi, Alo, W3hi, W3lo, b3, (float*)d_out);
}

// Round 5
// 240.490 us; speedup vs baseline: 2.1119x; 1.0211x over previous
//
#include <hip/hip_runtime.h>
#include <hip/hip_fp16.h>

// GraphSAGE 3-layer (mean aggr): N=50000, E=800000, 5->64->64->32.
// Round 5: fp16 hidden storage (halves gather bytes; h fits per-XCD L2) and
// two-neighbor-per-issue gather (wave halves take alternate neighbors, one
// uint = 2 fp16 channels per lane). GEMM stays MFMA bf16 3-product split on
// fp32-accumulated means (fp32-grade). CSR build via bucketed counting sort.

#define N_NODES 50000
#define N_EDGES 800000
#define IN_C 5
#define HID_C 64
#define OUT_C 32

#define NB 196        // buckets of 256 nodes (dst >> 8)
#define BCAP 6144     // per-bucket region capacity (mean 4082, sigma ~64)
#define BWG 256       // k_bucket workgroups
#define BCH (N_EDGES / BWG)  // 3125 edges per workgroup

typedef __attribute__((ext_vector_type(8))) short bf16x8;   // 8 bf16 = 4 VGPRs
typedef __attribute__((ext_vector_type(4))) float f32x4;    // 4 fp32 acc

__device__ __forceinline__ int rfl(int v) { return __builtin_amdgcn_readfirstlane(v); }
__device__ __forceinline__ float lanebc(float v, int l) {
    return __int_as_float(__builtin_amdgcn_readlane(__float_as_int(v), l));
}
__device__ __forceinline__ unsigned short f2bf(float f) {  // RNE
    unsigned u = __float_as_uint(f);
    return (unsigned short)((u + 0x7fffu + ((u >> 16) & 1u)) >> 16);
}
__device__ __forceinline__ float bf2f(unsigned short b) {
    return __uint_as_float(((unsigned)b) << 16);
}
__device__ __forceinline__ float2 unpk_h2(unsigned u) {
    __half2 h = *(__half2*)&u;
    return __half22float2(h);
}

// ---------------- CSR build: bucketed counting sort ----------------

__global__ __launch_bounds__(256) void k_bucket(const int* __restrict__ ei,
                                                int* __restrict__ gcur,
                                                int* __restrict__ ebuf) {
    __shared__ int hist[NB];
    __shared__ int base[NB];
    const int t = threadIdx.x;
    const int c0 = blockIdx.x * BCH;
    const int c1 = c0 + BCH;
    if (t < NB) hist[t] = 0;
    __syncthreads();
    for (int e = c0 + t; e < c1; e += 256) {
        int d = ei[N_EDGES + e];
        atomicAdd(&hist[d >> 8], 1);
    }
    __syncthreads();
    if (t < NB) {
        base[t] = atomicAdd(&gcur[t], hist[t]);
        hist[t] = 0;  // reuse as local cursor
    }
    __syncthreads();
    for (int e = c0 + t; e < c1; e += 256) {
        int d = ei[N_EDGES + e];
        int s = ei[e];
        int b = d >> 8;
        int p = base[b] + atomicAdd(&hist[b], 1);
        if (p < BCAP) ebuf[b * BCAP + p] = ((d & 255) << 16) | s;
    }
}

__global__ __launch_bounds__(256) void k_bscan(const int* __restrict__ gcur,
                                               int* __restrict__ bbase,
                                               int* __restrict__ row_off) {
    __shared__ int s[256];
    int t = threadIdx.x;
    s[t] = (t < NB) ? gcur[t] : 0;
    __syncthreads();
#pragma unroll
    for (int o = 1; o < 256; o <<= 1) {
        int v = s[t];
        int a = (t >= o) ? s[t - o] : 0;
        __syncthreads();
        s[t] = v + a;
        __syncthreads();
    }
    if (t < NB) bbase[t] = (t == 0) ? 0 : s[t - 1];
    if (t == 0) row_off[N_NODES] = N_EDGES;
}

__global__ __launch_bounds__(256) void k_bsort(const int* __restrict__ gcur,
                                               const int* __restrict__ bbase,
                                               const int* __restrict__ ebuf,
                                               int* __restrict__ row_off,
                                               float* __restrict__ inv_deg,
                                               int* __restrict__ srcs) {
    __shared__ int cnt[256];
    __shared__ int loff[256];
    __shared__ int cur[256];
    __shared__ int stage[BCAP];
    const int t = threadIdx.x;
    const int b = blockIdx.x;
    const int n = gcur[b] < BCAP ? gcur[b] : BCAP;
    const int base = bbase[b];
    const int node0 = b << 8;
    const int* eb = ebuf + b * BCAP;

    cnt[t] = 0;
    __syncthreads();
    for (int i = t; i < n; i += 256) atomicAdd(&cnt[(eb[i] >> 16) & 255], 1);
    __syncthreads();
    loff[t] = cnt[t];
    __syncthreads();
#pragma unroll
    for (int o = 1; o < 256; o <<= 1) {
        int v = loff[t];
        int a = (t >= o) ? loff[t - o] : 0;
        __syncthreads();
        loff[t] = v + a;
        __syncthreads();
    }
    int ex = loff[t] - cnt[t];  // exclusive
    cur[t] = ex;
    int node = node0 + t;
    if (node < N_NODES) {
        row_off[node] = base + ex;
        int d = cnt[t];
        inv_deg[node] = 1.0f / (float)(d > 1 ? d : 1);
    }
    __syncthreads();
    for (int i = t; i < n; i += 256) {
        int v = eb[i];
        int p = atomicAdd(&cur[(v >> 16) & 255], 1);
        stage[p] = v & 0xFFFF;
    }
    __syncthreads();
    for (int i = t; i < n; i += 256) srcs[base + i] = stage[i];
}

// ---------------- weight prep: Wcat = [Wl | Wr], bf16 hi/lo split ----------
// Also zeroes gcur for k_bucket (same stream, runs before it).

__global__ __launch_bounds__(256) void k_prep(
    const float* __restrict__ W2l, const float* __restrict__ W2r,
    const float* __restrict__ W3l, const float* __restrict__ W3r,
    unsigned short* __restrict__ W2hi, unsigned short* __restrict__ W2lo,
    unsigned short* __restrict__ W3hi, unsigned short* __restrict__ W3lo,
    int* __restrict__ gcur) {
    int t = blockIdx.x * 256 + threadIdx.x;
    int stride = gridDim.x * 256;
    if (blockIdx.x == 0 && threadIdx.x < NB) gcur[threadIdx.x] = 0;
    for (int p = t; p < 64 * 128; p += stride) {
        int j = p >> 7, k = p & 127;
        float w = (k < 64) ? W2l[j * 64 + k] : W2r[j * 64 + (k - 64)];
        unsigned short h = f2bf(w);
        W2hi[p] = h;
        W2lo[p] = f2bf(w - bf2f(h));
    }
    for (int p = t; p < 32 * 128; p += stride) {
        int j = p >> 7, k = p & 127;
        float w = (k < 64) ? W3l[j * 64 + k] : W3r[j * 64 + (k - 64)];
        unsigned short h = f2bf(w);
        W3hi[p] = h;
        W3lo[p] = f2bf(w - bf2f(h));
    }
}

// ---------------- Layer 1: 5 -> 64 fused, ReLU, fp16 output ----------------

__global__ __launch_bounds__(512) void k_layer1(
    const float* __restrict__ x, const int* __restrict__ row_off,
    const int* __restrict__ srcs, const float* __restrict__ inv_deg,
    const float* __restrict__ W1l, const float* __restrict__ b1,
    const float* __restrict__ W1r, __half* __restrict__ h1) {
    const int t = threadIdx.x;
    const int lane = t & 63;
    const int v = blockIdx.x * 8 + (t >> 6);
    if (v >= N_NODES) return;

    float wl[IN_C], wr[IN_C];
#pragma unroll
    for (int i = 0; i < IN_C; ++i) {
        wl[i] = W1l[lane * IN_C + i];
        wr[i] = W1r[lane * IN_C + i];
    }
    float bb = b1[lane];

    int beg = rfl(row_off[v]);
    int end = rfl(row_off[v + 1]);
    float sum = 0.f;
    int e = beg;
    int e8 = beg + ((end - beg) & ~7);
    for (; e < e8; e += 8) {
        int s0 = srcs[e + 0], s1 = srcs[e + 1], s2 = srcs[e + 2], s3 = srcs[e + 3];
        int s4 = srcs[e + 4], s5 = srcs[e + 5], s6 = srcs[e + 6], s7 = srcs[e + 7];
        float a0 = (lane < IN_C) ? x[s0 * IN_C + lane] : 0.f;
        float a1 = (lane < IN_C) ? x[s1 * IN_C + lane] : 0.f;
        float a2 = (lane < IN_C) ? x[s2 * IN_C + lane] : 0.f;
        float a3 = (lane < IN_C) ? x[s3 * IN_C + lane] : 0.f;
        float a4 = (lane < IN_C) ? x[s4 * IN_C + lane] : 0.f;
        float a5 = (lane < IN_C) ? x[s5 * IN_C + lane] : 0.f;
        float a6 = (lane < IN_C) ? x[s6 * IN_C + lane] : 0.f;
        float a7 = (lane < IN_C) ? x[s7 * IN_C + lane] : 0.f;
        sum += ((a0 + a1) + (a2 + a3)) + ((a4 + a5) + (a6 + a7));
    }
    for (; e < end; ++e) {
        int s0 = srcs[e];
        if (lane < IN_C) sum += x[s0 * IN_C + lane];
    }
    float xv = (lane < IN_C) ? x[v * IN_C + lane] : 0.f;
    float summ = sum * inv_deg[v];
    float acc = bb;
#pragma unroll
    for (int i = 0; i < IN_C; ++i) {
        acc += wl[i] * lanebc(summ, i);
        acc += wr[i] * lanebc(xv, i);
    }
    h1[v * HID_C + lane] = __float2half(fmaxf(acc, 0.f));
}

// ---------------- gather: h[N,64] fp16 -> A[N,128] bf16 hi/lo ([mean || x]) --
// One wave per node; wave halves take alternate neighbors; each lane reads one
// uint (2 fp16 channels). fp32 accumulate, __shfl_xor(32) combine. Half 0
// writes the mean part of A, half 1 the root part (bf16 hi/lo split, packed
// uint stores).

__global__ __launch_bounds__(256) void k_gather(
    const __half* __restrict__ h, const int* __restrict__ row_off,
    const int* __restrict__ srcs, const float* __restrict__ inv_deg,
    unsigned short* __restrict__ Ahi, unsigned short* __restrict__ Alo) {
    const int lane = threadIdx.x & 63;
    const int ll = lane & 31;
    const int hf = lane >> 5;
    const int v = blockIdx.x * 4 + (threadIdx.x >> 6);
    if (v >= N_NODES) return;
    const unsigned* h32 = (const unsigned*)h;  // row stride 32 uints

    int beg = rfl(row_off[v]);
    int end = rfl(row_off[v + 1]);
    float s0 = 0.f, s1 = 0.f;
    int e = beg;
    int e8 = beg + ((end - beg) & ~7);
    for (; e < e8; e += 8) {
        int n0 = srcs[e + 0 + hf];
        int n1 = srcs[e + 2 + hf];
        int n2 = srcs[e + 4 + hf];
        int n3 = srcs[e + 6 + hf];
        unsigned u0 = h32[n0 * 32 + ll];
        unsigned u1 = h32[n1 * 32 + ll];
        unsigned u2 = h32[n2 * 32 + ll];
        unsigned u3 = h32[n3 * 32 + ll];
        float2 f0 = unpk_h2(u0);
        float2 f1 = unpk_h2(u1);
        float2 f2 = unpk_h2(u2);
        float2 f3 = unpk_h2(u3);
        s0 += (f0.x + f1.x) + (f2.x + f3.x);
        s1 += (f0.y + f1.y) + (f2.y + f3.y);
    }
    for (; e + 2 <= end; e += 2) {
        int n0 = srcs[e + hf];
        float2 f0 = unpk_h2(h32[n0 * 32 + ll]);
        s0 += f0.x;
        s1 += f0.y;
    }
    if (e < end && hf == 0) {
        int n0 = srcs[e];
        float2 f0 = unpk_h2(h32[n0 * 32 + ll]);
        s0 += f0.x;
        s1 += f0.y;
    }
    s0 += __shfl_xor(s0, 32, 64);
    s1 += __shfl_xor(s1, 32, 64);

    float2 xr = unpk_h2(h32[v * 32 + ll]);
    float idg = inv_deg[v];
    float m0 = s0 * idg, m1 = s1 * idg;

    unsigned short mh0 = f2bf(m0), ml0 = f2bf(m0 - bf2f(mh0));
    unsigned short mh1 = f2bf(m1), ml1 = f2bf(m1 - bf2f(mh1));
    unsigned short xh0 = f2bf(xr.x), xl0 = f2bf(xr.x - bf2f(xh0));
    unsigned short xh1 = f2bf(xr.y), xl1 = f2bf(xr.y - bf2f(xh1));

    unsigned* AhiRow = (unsigned*)(Ahi + (size_t)v * 128);
    unsigned* AloRow = (unsigned*)(Alo + (size_t)v * 128);
    if (hf == 0) {
        AhiRow[ll] = (unsigned)mh0 | ((unsigned)mh1 << 16);
        AloRow[ll] = (unsigned)ml0 | ((unsigned)ml1 << 16);
    } else {
        AhiRow[32 + ll] = (unsigned)xh0 | ((unsigned)xh1 << 16);
        AloRow[32 + ll] = (unsigned)xl0 | ((unsigned)xl1 << 16);
    }
}

// ---------------- GEMM: out[N,DOUT] = A[N,128] @ Wcat[DOUT,128]^T + b -------

template <typename T> __device__ __forceinline__ T cvt_out(float v);
template <> __device__ __forceinline__ float cvt_out<float>(float v) { return v; }
template <> __device__ __forceinline__ __half cvt_out<__half>(float v) { return __float2half(v); }

template <int DOUT, bool RELU, typename OutT>
__global__ __launch_bounds__(256) void k_gemm(
    const unsigned short* __restrict__ Ahi, const unsigned short* __restrict__ Alo,
    const unsigned short* __restrict__ Whi, const unsigned short* __restrict__ Wlo,
    const float* __restrict__ bias, OutT* __restrict__ out) {
    constexpr int NT = DOUT / 16;
    const int lane = threadIdx.x & 63;
    const int tile = blockIdx.x * 4 + (threadIdx.x >> 6);
    if (tile >= N_NODES / 16) return;
    const int node0 = tile * 16;
    const int r = lane & 15;
    const int quad = lane >> 4;

    f32x4 acc[NT];
#pragma unroll
    for (int n = 0; n < NT; ++n) acc[n] = (f32x4){0.f, 0.f, 0.f, 0.f};

    const size_t abase = ((size_t)(node0 + r)) * 128 + quad * 8;
#pragma unroll
    for (int ks = 0; ks < 4; ++ks) {
        bf16x8 ah = *(const bf16x8*)(Ahi + abase + ks * 32);
        bf16x8 al = *(const bf16x8*)(Alo + abase + ks * 32);
#pragma unroll
        for (int n = 0; n < NT; ++n) {
            const size_t wbase = ((size_t)(n * 16 + r)) * 128 + ks * 32 + quad * 8;
            bf16x8 bh = *(const bf16x8*)(Whi + wbase);
            bf16x8 bl = *(const bf16x8*)(Wlo + wbase);
            acc[n] = __builtin_amdgcn_mfma_f32_16x16x32_bf16(ah, bh, acc[n], 0, 0, 0);
            acc[n] = __builtin_amdgcn_mfma_f32_16x16x32_bf16(ah, bl, acc[n], 0, 0, 0);
            acc[n] = __builtin_amdgcn_mfma_f32_16x16x32_bf16(al, bh, acc[n], 0, 0, 0);
        }
    }
#pragma unroll
    for (int n = 0; n < NT; ++n) {
        float bv = bias[n * 16 + r];
#pragma unroll
        for (int g = 0; g < 4; ++g) {
            int m = quad * 4 + g;
            float vacc = acc[n][g] + bv;
            if (RELU) vacc = fmaxf(vacc, 0.f);
            out[(size_t)(node0 + m) * DOUT + n * 16 + r] = cvt_out<OutT>(vacc);
        }
    }
}

// ---------------- launch ----------------

extern "C" void kernel_launch(void* const* d_in, const int* in_sizes, int n_in,
                              void* d_out, int out_size, void* d_ws, size_t ws_size,
                              hipStream_t stream) {
    const float* x   = (const float*)d_in[0];
    const int*   ei  = (const int*)d_in[1];  // [2,E]: row0=src, row1=dst
    const float* W1l = (const float*)d_in[2];
    const float* b1  = (const float*)d_in[3];
    const float* W1r = (const float*)d_in[4];
    const float* W2l = (const float*)d_in[5];
    const float* b2  = (const float*)d_in[6];
    const float* W2r = (const float*)d_in[7];
    const float* W3l = (const float*)d_in[8];
    const float* b3  = (const float*)d_in[9];
    const float* W3r = (const float*)d_in[10];

    char* ws = (char*)d_ws;
    size_t off = 0;
    auto alloc = [&](size_t bytes) -> char* {
        char* p = ws + off;
        off += (bytes + 255) & ~(size_t)255;
        return p;
    };
    int*   gcur   = (int*)alloc(NB * sizeof(int));
    int*   bbase  = (int*)alloc(NB * sizeof(int));
    int*   rowoff = (int*)alloc((N_NODES + 1) * sizeof(int));
    float* invdeg = (float*)alloc(N_NODES * sizeof(float));
    int*   srcs   = (int*)alloc(N_EDGES * sizeof(int));
    __half* h1    = (__half*)alloc((size_t)N_NODES * HID_C * sizeof(__half));
    unsigned short* Ahi = (unsigned short*)alloc((size_t)N_NODES * 128 * 2);
    unsigned short* Alo = (unsigned short*)alloc((size_t)N_NODES * 128 * 2);
    unsigned short* W2hi = (unsigned short*)alloc(64 * 128 * 2);
    unsigned short* W2lo = (unsigned short*)alloc(64 * 128 * 2);
    unsigned short* W3hi = (unsigned short*)alloc(32 * 128 * 2);
    unsigned short* W3lo = (unsigned short*)alloc(32 * 128 * 2);
    __half* h2 = h1;                // h1 fully consumed before h2 is written
    int*    ebuf = (int*)Ahi;       // ebuf (4.8 MB) dead before Ahi is written

    // CSR build (k_prep also zeroes gcur; same-stream ordering)
    k_prep<<<dim3(48), dim3(256), 0, stream>>>(W2l, W2r, W3l, W3r,
                                               W2hi, W2lo, W3hi, W3lo, gcur);
    k_bucket<<<dim3(BWG), dim3(256), 0, stream>>>(ei, gcur, ebuf);
    k_bscan<<<dim3(1), dim3(256), 0, stream>>>(gcur, bbase, rowoff);
    k_bsort<<<dim3(NB), dim3(256), 0, stream>>>(gcur, bbase, ebuf, rowoff, invdeg, srcs);

    // layer 1 (fused): x -> h1 (fp16)
    k_layer1<<<dim3((N_NODES + 7) / 8), dim3(512), 0, stream>>>(
        x, rowoff, srcs, invdeg, W1l, b1, W1r, h1);

    // layer 2: gather(h1) -> A; gemm -> h2 (fp16, ReLU)
    k_gather<<<dim3((N_NODES + 3) / 4), dim3(256), 0, stream>>>(
        h1, rowoff, srcs, invdeg, Ahi, Alo);
    k_gemm<HID_C, true, __half><<<dim3((N_NODES / 16 + 3) / 4), dim3(256), 0, stream>>>(
        Ahi, Alo, W2hi, W2lo, b2, h2);

    // layer 3: gather(h2) -> A; gemm -> out (fp32)
    k_gather<<<dim3((N_NODES + 3) / 4), dim3(256), 0, stream>>>(
        h2, rowoff, srcs, invdeg, Ahi, Alo);
    k_gemm<OUT_C, false, float><<<dim3((N_NODES / 16 + 3) / 4), dim3(256), 0, stream>>>(
        Ahi, Alo, W3hi, W3lo, b3, (float*)d_out);
}

// Round 6
// 215.802 us; speedup vs baseline: 2.3535x; 1.1144x over previous
//
#include <hip/hip_runtime.h>
#include <hip/hip_fp16.h>

// GraphSAGE 3-layer (mean aggr): N=50000, E=800000, 5->64->64->32.
// Round 6:
//  - k_bucket v2: LDS-staged counting sort per wg -> bucket-contiguous burst
//    writes (kills the ~16x partial-line write amplification).
//  - k_bsort absorbs the bucket-count scan (one less dispatch).
//  - k_fused: gather-mean + MFMA GEMM in one kernel via LDS (no A round-trip).
//    h2 is a separate buffer (fused kernel reads h1 while writing h2).

#define N_NODES 50000
#define N_EDGES 800000
#define IN_C 5
#define HID_C 64
#define OUT_C 32

#define NB 196        // buckets of 256 nodes (dst >> 8)
#define BCAP 6144     // per-bucket region capacity (mean 4082, sigma ~64)
#define BWG 256       // k_bucket workgroups
#define BCH (N_EDGES / BWG)  // 3125 edges per workgroup

typedef __attribute__((ext_vector_type(8))) short bf16x8;   // 8 bf16 = 4 VGPRs
typedef __attribute__((ext_vector_type(4))) float f32x4;    // 4 fp32 acc

__device__ __forceinline__ int rfl(int v) { return __builtin_amdgcn_readfirstlane(v); }
__device__ __forceinline__ float lanebc(float v, int l) {
    return __int_as_float(__builtin_amdgcn_readlane(__float_as_int(v), l));
}
__device__ __forceinline__ unsigned short f2bf(float f) {  // RNE
    unsigned u = __float_as_uint(f);
    return (unsigned short)((u + 0x7fffu + ((u >> 16) & 1u)) >> 16);
}
__device__ __forceinline__ float bf2f(unsigned short b) {
    return __uint_as_float(((unsigned)b) << 16);
}
__device__ __forceinline__ float2 unpk_h2(unsigned u) {
    __half2 h = *(__half2*)&u;
    return __half22float2(h);
}

// ---------------- CSR build ----------------

// Phase A: per-wg LDS counting sort of 3125 edges by coarse bucket, then
// bucket-contiguous burst copy to reserved global ranges (low write amp).
__global__ __launch_bounds__(256) void k_bucket(const int* __restrict__ ei,
                                                int* __restrict__ gcur,
                                                unsigned* __restrict__ ebuf) {
    __shared__ int hist[NB];
    __shared__ int loff[NB];
    __shared__ int cur[NB];
    __shared__ int gbase[NB];
    __shared__ int scanb[256];
    __shared__ unsigned stage[BCH];
    const int t = threadIdx.x;
    const int c0 = blockIdx.x * BCH;

    if (t < NB) hist[t] = 0;
    __syncthreads();
    for (int i = t; i < BCH; i += 256) {
        int d = ei[N_EDGES + c0 + i];
        atomicAdd(&hist[d >> 8], 1);
    }
    __syncthreads();
    scanb[t] = (t < NB) ? hist[t] : 0;
    __syncthreads();
#pragma unroll
    for (int o = 1; o < 256; o <<= 1) {
        int v = scanb[t];
        int a = (t >= o) ? scanb[t - o] : 0;
        __syncthreads();
        scanb[t] = v + a;
        __syncthreads();
    }
    if (t < NB) {
        int ex = (t == 0) ? 0 : scanb[t - 1];
        loff[t] = ex;
        cur[t] = ex;
        gbase[t] = atomicAdd(&gcur[t], hist[t]);
    }
    __syncthreads();
    for (int i = t; i < BCH; i += 256) {
        int d = ei[N_EDGES + c0 + i];
        int s = ei[c0 + i];
        int b = d >> 8;
        int p = atomicAdd(&cur[b], 1);
        stage[p] = ((unsigned)d << 16) | (unsigned)s;
    }
    __syncthreads();
    for (int i = t; i < BCH; i += 256) {
        unsigned ev = stage[i];
        int b = ev >> 24;
        int pos = gbase[b] + (i - loff[b]);
        if (pos < BCAP) ebuf[b * BCAP + pos] = ev;
    }
}

// Phase B: per-bucket counting sort by dstlow; inlines the bucket-count scan.
// Emits row_off + inv_deg for the bucket's 256 nodes and coalesced srcs.
__global__ __launch_bounds__(256) void k_bsort(const int* __restrict__ gcur,
                                               const unsigned* __restrict__ ebuf,
                                               int* __restrict__ row_off,
                                               float* __restrict__ inv_deg,
                                               int* __restrict__ srcs) {
    __shared__ int sc[256];
    __shared__ int cnt[256];
    __shared__ int loff[256];
    __shared__ int cur[256];
    __shared__ int stage[BCAP];
    const int t = threadIdx.x;
    const int b = blockIdx.x;

    sc[t] = (t < NB) ? gcur[t] : 0;
    __syncthreads();
#pragma unroll
    for (int o = 1; o < 256; o <<= 1) {
        int v = sc[t];
        int a = (t >= o) ? sc[t - o] : 0;
        __syncthreads();
        sc[t] = v + a;
        __syncthreads();
    }
    const int base = (b == 0) ? 0 : sc[b - 1];
    const int nraw = gcur[b];
    const int n = nraw < BCAP ? nraw : BCAP;
    const int node0 = b << 8;
    const unsigned* eb = ebuf + b * BCAP;

    cnt[t] = 0;
    __syncthreads();
    for (int i = t; i < n; i += 256) atomicAdd(&cnt[(eb[i] >> 16) & 255], 1);
    __syncthreads();
    loff[t] = cnt[t];
    __syncthreads();
#pragma unroll
    for (int o = 1; o < 256; o <<= 1) {
        int v = loff[t];
        int a = (t >= o) ? loff[t - o] : 0;
        __syncthreads();
        loff[t] = v + a;
        __syncthreads();
    }
    int ex = loff[t] - cnt[t];  // exclusive
    cur[t] = ex;
    int node = node0 + t;
    if (node < N_NODES) {
        row_off[node] = base + ex;
        int d = cnt[t];
        inv_deg[node] = 1.0f / (float)(d > 1 ? d : 1);
    }
    if (b == 0 && t == 0) row_off[N_NODES] = N_EDGES;
    __syncthreads();
    for (int i = t; i < n; i += 256) {
        unsigned ev = eb[i];
        int p = atomicAdd(&cur[(ev >> 16) & 255], 1);
        stage[p] = (int)(ev & 0xFFFFu);
    }
    __syncthreads();
    for (int i = t; i < n; i += 256) srcs[base + i] = stage[i];
}

// ---------------- weight prep: Wcat = [Wl | Wr], bf16 hi/lo split ----------
// Also zeroes gcur for k_bucket (same stream, runs before it).

__global__ __launch_bounds__(256) void k_prep(
    const float* __restrict__ W2l, const float* __restrict__ W2r,
    const float* __restrict__ W3l, const float* __restrict__ W3r,
    unsigned short* __restrict__ W2hi, unsigned short* __restrict__ W2lo,
    unsigned short* __restrict__ W3hi, unsigned short* __restrict__ W3lo,
    int* __restrict__ gcur) {
    int t = blockIdx.x * 256 + threadIdx.x;
    int stride = gridDim.x * 256;
    if (blockIdx.x == 0 && threadIdx.x < NB) gcur[threadIdx.x] = 0;
    for (int p = t; p < 64 * 128; p += stride) {
        int j = p >> 7, k = p & 127;
        float w = (k < 64) ? W2l[j * 64 + k] : W2r[j * 64 + (k - 64)];
        unsigned short h = f2bf(w);
        W2hi[p] = h;
        W2lo[p] = f2bf(w - bf2f(h));
    }
    for (int p = t; p < 32 * 128; p += stride) {
        int j = p >> 7, k = p & 127;
        float w = (k < 64) ? W3l[j * 64 + k] : W3r[j * 64 + (k - 64)];
        unsigned short h = f2bf(w);
        W3hi[p] = h;
        W3lo[p] = f2bf(w - bf2f(h));
    }
}

// ---------------- Layer 1: 5 -> 64 fused matvec, ReLU, fp16 output ---------

__global__ __launch_bounds__(512) void k_layer1(
    const float* __restrict__ x, const int* __restrict__ row_off,
    const int* __restrict__ srcs, const float* __restrict__ inv_deg,
    const float* __restrict__ W1l, const float* __restrict__ b1,
    const float* __restrict__ W1r, __half* __restrict__ h1) {
    const int t = threadIdx.x;
    const int lane = t & 63;
    const int v = blockIdx.x * 8 + (t >> 6);
    if (v >= N_NODES) return;

    float wl[IN_C], wr[IN_C];
#pragma unroll
    for (int i = 0; i < IN_C; ++i) {
        wl[i] = W1l[lane * IN_C + i];
        wr[i] = W1r[lane * IN_C + i];
    }
    float bb = b1[lane];

    int beg = rfl(row_off[v]);
    int end = rfl(row_off[v + 1]);
    float sum = 0.f;
    int e = beg;
    int e8 = beg + ((end - beg) & ~7);
    for (; e < e8; e += 8) {
        int s0 = srcs[e + 0], s1 = srcs[e + 1], s2 = srcs[e + 2], s3 = srcs[e + 3];
        int s4 = srcs[e + 4], s5 = srcs[e + 5], s6 = srcs[e + 6], s7 = srcs[e + 7];
        float a0 = (lane < IN_C) ? x[s0 * IN_C + lane] : 0.f;
        float a1 = (lane < IN_C) ? x[s1 * IN_C + lane] : 0.f;
        float a2 = (lane < IN_C) ? x[s2 * IN_C + lane] : 0.f;
        float a3 = (lane < IN_C) ? x[s3 * IN_C + lane] : 0.f;
        float a4 = (lane < IN_C) ? x[s4 * IN_C + lane] : 0.f;
        float a5 = (lane < IN_C) ? x[s5 * IN_C + lane] : 0.f;
        float a6 = (lane < IN_C) ? x[s6 * IN_C + lane] : 0.f;
        float a7 = (lane < IN_C) ? x[s7 * IN_C + lane] : 0.f;
        sum += ((a0 + a1) + (a2 + a3)) + ((a4 + a5) + (a6 + a7));
    }
    for (; e < end; ++e) {
        int s0 = srcs[e];
        if (lane < IN_C) sum += x[s0 * IN_C + lane];
    }
    float xv = (lane < IN_C) ? x[v * IN_C + lane] : 0.f;
    float summ = sum * inv_deg[v];
    float acc = bb;
#pragma unroll
    for (int i = 0; i < IN_C; ++i) {
        acc += wl[i] * lanebc(summ, i);
        acc += wr[i] * lanebc(xv, i);
    }
    h1[v * HID_C + lane] = __float2half(fmaxf(acc, 0.f));
}

// ---------------- fused gather + GEMM (layers 2/3) ----------------
// Block = 4 waves = 16 nodes. Each wave gathers 4 nodes (fp16 reads, fp32
// accumulate, wave halves on alternate neighbors) and writes [mean||x] as
// bf16 hi/lo rows into LDS (row stride 136 ushorts: rows r,r+8 share banks =
// 2-way = free). One barrier, then wave n (n < DOUT/16) computes the 16x16
// output tile n with 12 MFMAs (bf16 3-product split, fp32-grade).

template <typename T> __device__ __forceinline__ T cvt_out(float v);
template <> __device__ __forceinline__ float cvt_out<float>(float v) { return v; }
template <> __device__ __forceinline__ __half cvt_out<__half>(float v) { return __float2half(v); }

template <int DOUT, bool RELU, typename OutT>
__global__ __launch_bounds__(256) void k_fused(
    const __half* __restrict__ h, const int* __restrict__ row_off,
    const int* __restrict__ srcs, const float* __restrict__ inv_deg,
    const unsigned short* __restrict__ Whi, const unsigned short* __restrict__ Wlo,
    const float* __restrict__ bias, OutT* __restrict__ out) {
    constexpr int AP = 136;  // padded LDS row stride (ushorts)
    __shared__ __align__(16) unsigned short Ah[16][AP];
    __shared__ __align__(16) unsigned short Al[16][AP];
    const int t = threadIdx.x;
    const int lane = t & 63;
    const int w = t >> 6;
    const int ll = lane & 31;
    const int hf = lane >> 5;
    const int node0 = blockIdx.x * 16;  // N_NODES = 3125*16 exactly
    const unsigned* h32 = (const unsigned*)h;  // row stride 32 uints

    for (int m = w * 4; m < w * 4 + 4; ++m) {
        const int v = node0 + m;
        int beg = rfl(row_off[v]);
        int end = rfl(row_off[v + 1]);
        float s0 = 0.f, s1 = 0.f;
        int e = beg;
        int e8 = beg + ((end - beg) & ~7);
        for (; e < e8; e += 8) {
            int n0 = srcs[e + 0 + hf];
            int n1 = srcs[e + 2 + hf];
            int n2 = srcs[e + 4 + hf];
            int n3 = srcs[e + 6 + hf];
            float2 f0 = unpk_h2(h32[n0 * 32 + ll]);
            float2 f1 = unpk_h2(h32[n1 * 32 + ll]);
            float2 f2 = unpk_h2(h32[n2 * 32 + ll]);
            float2 f3 = unpk_h2(h32[n3 * 32 + ll]);
            s0 += (f0.x + f1.x) + (f2.x + f3.x);
            s1 += (f0.y + f1.y) + (f2.y + f3.y);
        }
        for (; e + 2 <= end; e += 2) {
            float2 f0 = unpk_h2(h32[srcs[e + hf] * 32 + ll]);
            s0 += f0.x;
            s1 += f0.y;
        }
        if (e < end && hf == 0) {
            float2 f0 = unpk_h2(h32[srcs[e] * 32 + ll]);
            s0 += f0.x;
            s1 += f0.y;
        }
        s0 += __shfl_xor(s0, 32, 64);
        s1 += __shfl_xor(s1, 32, 64);

        float2 xr = unpk_h2(h32[v * 32 + ll]);
        float idg = inv_deg[v];
        float m0 = s0 * idg, m1 = s1 * idg;

        unsigned* AhR = (unsigned*)&Ah[m][0];
        unsigned* AlR = (unsigned*)&Al[m][0];
        if (hf == 0) {
            unsigned short h0 = f2bf(m0), h1v = f2bf(m1);
            unsigned short l0 = f2bf(m0 - bf2f(h0)), l1 = f2bf(m1 - bf2f(h1v));
            AhR[ll] = (unsigned)h0 | ((unsigned)h1v << 16);
            AlR[ll] = (unsigned)l0 | ((unsigned)l1 << 16);
        } else {
            unsigned short h0 = f2bf(xr.x), h1v = f2bf(xr.y);
            unsigned short l0 = f2bf(xr.x - bf2f(h0)), l1 = f2bf(xr.y - bf2f(h1v));
            AhR[32 + ll] = (unsigned)h0 | ((unsigned)h1v << 16);
            AlR[32 + ll] = (unsigned)l0 | ((unsigned)l1 << 16);
        }
    }
    __syncthreads();

    constexpr int NT = DOUT / 16;
    if (w < NT) {
        const int r = lane & 15;
        const int quad = lane >> 4;
        f32x4 acc = (f32x4){0.f, 0.f, 0.f, 0.f};
#pragma unroll
        for (int ks = 0; ks < 4; ++ks) {
            bf16x8 ah = *(const bf16x8*)&Ah[r][ks * 32 + quad * 8];
            bf16x8 al = *(const bf16x8*)&Al[r][ks * 32 + quad * 8];
            const size_t wb = ((size_t)(w * 16 + r)) * 128 + ks * 32 + quad * 8;
            bf16x8 bh = *(const bf16x8*)(Whi + wb);
            bf16x8 bl = *(const bf16x8*)(Wlo + wb);
            acc = __builtin_amdgcn_mfma_f32_16x16x32_bf16(ah, bh, acc, 0, 0, 0);
            acc = __builtin_amdgcn_mfma_f32_16x16x32_bf16(ah, bl, acc, 0, 0, 0);
            acc = __builtin_amdgcn_mfma_f32_16x16x32_bf16(al, bh, acc, 0, 0, 0);
        }
        float bv = bias[w * 16 + r];
#pragma unroll
        for (int g = 0; g < 4; ++g) {
            int m = quad * 4 + g;
            float vv = acc[g] + bv;
            if (RELU) vv = fmaxf(vv, 0.f);
            out[(size_t)(node0 + m) * DOUT + w * 16 + r] = cvt_out<OutT>(vv);
        }
    }
}

// ---------------- launch ----------------

extern "C" void kernel_launch(void* const* d_in, const int* in_sizes, int n_in,
                              void* d_out, int out_size, void* d_ws, size_t ws_size,
                              hipStream_t stream) {
    const float* x   = (const float*)d_in[0];
    const int*   ei  = (const int*)d_in[1];  // [2,E]: row0=src, row1=dst
    const float* W1l = (const float*)d_in[2];
    const float* b1  = (const float*)d_in[3];
    const float* W1r = (const float*)d_in[4];
    const float* W2l = (const float*)d_in[5];
    const float* b2  = (const float*)d_in[6];
    const float* W2r = (const float*)d_in[7];
    const float* W3l = (const float*)d_in[8];
    const float* b3  = (const float*)d_in[9];
    const float* W3r = (const float*)d_in[10];

    char* ws = (char*)d_ws;
    size_t off = 0;
    auto alloc = [&](size_t bytes) -> char* {
        char* p = ws + off;
        off += (bytes + 255) & ~(size_t)255;
        return p;
    };
    int*      gcur   = (int*)alloc(NB * sizeof(int));
    int*      rowoff = (int*)alloc((N_NODES + 1) * sizeof(int));
    float*    invdeg = (float*)alloc(N_NODES * sizeof(float));
    int*      srcs   = (int*)alloc(N_EDGES * sizeof(int));
    unsigned* ebuf   = (unsigned*)alloc((size_t)NB * BCAP * sizeof(unsigned));
    __half*   h1     = (__half*)alloc((size_t)N_NODES * HID_C * sizeof(__half));
    __half*   h2     = (__half*)alloc((size_t)N_NODES * HID_C * sizeof(__half));
    unsigned short* W2hi = (unsigned short*)alloc(64 * 128 * 2);
    unsigned short* W2lo = (unsigned short*)alloc(64 * 128 * 2);
    unsigned short* W3hi = (unsigned short*)alloc(32 * 128 * 2);
    unsigned short* W3lo = (unsigned short*)alloc(32 * 128 * 2);

    // CSR build (k_prep also zeroes gcur; same-stream ordering)
    k_prep<<<dim3(48), dim3(256), 0, stream>>>(W2l, W2r, W3l, W3r,
                                               W2hi, W2lo, W3hi, W3lo, gcur);
    k_bucket<<<dim3(BWG), dim3(256), 0, stream>>>(ei, gcur, ebuf);
    k_bsort<<<dim3(NB), dim3(256), 0, stream>>>(gcur, ebuf, rowoff, invdeg, srcs);

    // layer 1 (fused matvec): x -> h1 (fp16)
    k_layer1<<<dim3((N_NODES + 7) / 8), dim3(512), 0, stream>>>(
        x, rowoff, srcs, invdeg, W1l, b1, W1r, h1);

    // layer 2: fused gather+gemm, h1 -> h2 (fp16, ReLU)
    k_fused<HID_C, true, __half><<<dim3(N_NODES / 16), dim3(256), 0, stream>>>(
        h1, rowoff, srcs, invdeg, W2hi, W2lo, b2, h2);

    // layer 3: fused gather+gemm, h2 -> out (fp32)
    k_fused<OUT_C, false, float><<<dim3(N_NODES / 16), dim3(256), 0, stream>>>(
        h2, rowoff, srcs, invdeg, W3hi, W3lo, b3, (float*)d_out);
}

// Round 7
// 215.439 us; speedup vs baseline: 2.3574x; 1.0017x over previous
//
#include <hip/hip_runtime.h>
#include <hip/hip_fp16.h>

// GraphSAGE 3-layer (mean aggr): N=50000, E=800000, 5->64->64->32.
// Round 7: widen gathers. k_fused reads 4 neighbor rows per instruction
// (dwordx2/lane, lane->(slot,channel-group), shfl_xor cross-slot reduce);
// k_layer1 reads 8 neighbor rows per instruction. CSR build via bucketed
// counting sort; GEMM = MFMA 16x16x32 bf16 3-product split (fp32-grade).

#define N_NODES 50000
#define N_EDGES 800000
#define IN_C 5
#define HID_C 64
#define OUT_C 32

#define NB 196        // buckets of 256 nodes (dst >> 8)
#define BCAP 6144     // per-bucket region capacity (mean 4082, sigma ~64)
#define BWG 256       // k_bucket workgroups
#define BCH (N_EDGES / BWG)  // 3125 edges per workgroup

typedef __attribute__((ext_vector_type(8))) short bf16x8;   // 8 bf16 = 4 VGPRs
typedef __attribute__((ext_vector_type(4))) float f32x4;    // 4 fp32 acc

__device__ __forceinline__ int rfl(int v) { return __builtin_amdgcn_readfirstlane(v); }
__device__ __forceinline__ float lanebc(float v, int l) {
    return __int_as_float(__builtin_amdgcn_readlane(__float_as_int(v), l));
}
__device__ __forceinline__ unsigned short f2bf(float f) {  // RNE
    unsigned u = __float_as_uint(f);
    return (unsigned short)((u + 0x7fffu + ((u >> 16) & 1u)) >> 16);
}
__device__ __forceinline__ float bf2f(unsigned short b) {
    return __uint_as_float(((unsigned)b) << 16);
}
__device__ __forceinline__ float2 unpk_h2(unsigned u) {
    __half2 h = *(__half2*)&u;
    return __half22float2(h);
}

// ---------------- CSR build ----------------

// Phase A: per-wg LDS counting sort of 3125 edges by coarse bucket, then
// bucket-contiguous burst copy to reserved global ranges (low write amp).
__global__ __launch_bounds__(256) void k_bucket(const int* __restrict__ ei,
                                                int* __restrict__ gcur,
                                                unsigned* __restrict__ ebuf) {
    __shared__ int hist[NB];
    __shared__ int loff[NB];
    __shared__ int cur[NB];
    __shared__ int gbase[NB];
    __shared__ int scanb[256];
    __shared__ unsigned stage[BCH];
    const int t = threadIdx.x;
    const int c0 = blockIdx.x * BCH;

    if (t < NB) hist[t] = 0;
    __syncthreads();
    for (int i = t; i < BCH; i += 256) {
        int d = ei[N_EDGES + c0 + i];
        atomicAdd(&hist[d >> 8], 1);
    }
    __syncthreads();
    scanb[t] = (t < NB) ? hist[t] : 0;
    __syncthreads();
#pragma unroll
    for (int o = 1; o < 256; o <<= 1) {
        int v = scanb[t];
        int a = (t >= o) ? scanb[t - o] : 0;
        __syncthreads();
        scanb[t] = v + a;
        __syncthreads();
    }
    if (t < NB) {
        int ex = (t == 0) ? 0 : scanb[t - 1];
        loff[t] = ex;
        cur[t] = ex;
        gbase[t] = atomicAdd(&gcur[t], hist[t]);
    }
    __syncthreads();
    for (int i = t; i < BCH; i += 256) {
        int d = ei[N_EDGES + c0 + i];
        int s = ei[c0 + i];
        int b = d >> 8;
        int p = atomicAdd(&cur[b], 1);
        stage[p] = ((unsigned)d << 16) | (unsigned)s;
    }
    __syncthreads();
    for (int i = t; i < BCH; i += 256) {
        unsigned ev = stage[i];
        int b = ev >> 24;
        int pos = gbase[b] + (i - loff[b]);
        if (pos < BCAP) ebuf[b * BCAP + pos] = ev;
    }
}

// Phase B: per-bucket counting sort by dstlow; inlines the bucket-count scan.
__global__ __launch_bounds__(256) void k_bsort(const int* __restrict__ gcur,
                                               const unsigned* __restrict__ ebuf,
                                               int* __restrict__ row_off,
                                               float* __restrict__ inv_deg,
                                               int* __restrict__ srcs) {
    __shared__ int sc[256];
    __shared__ int cnt[256];
    __shared__ int loff[256];
    __shared__ int cur[256];
    __shared__ int stage[BCAP];
    const int t = threadIdx.x;
    const int b = blockIdx.x;

    sc[t] = (t < NB) ? gcur[t] : 0;
    __syncthreads();
#pragma unroll
    for (int o = 1; o < 256; o <<= 1) {
        int v = sc[t];
        int a = (t >= o) ? sc[t - o] : 0;
        __syncthreads();
        sc[t] = v + a;
        __syncthreads();
    }
    const int base = (b == 0) ? 0 : sc[b - 1];
    const int nraw = gcur[b];
    const int n = nraw < BCAP ? nraw : BCAP;
    const int node0 = b << 8;
    const unsigned* eb = ebuf + b * BCAP;

    cnt[t] = 0;
    __syncthreads();
    for (int i = t; i < n; i += 256) atomicAdd(&cnt[(eb[i] >> 16) & 255], 1);
    __syncthreads();
    loff[t] = cnt[t];
    __syncthreads();
#pragma unroll
    for (int o = 1; o < 256; o <<= 1) {
        int v = loff[t];
        int a = (t >= o) ? loff[t - o] : 0;
        __syncthreads();
        loff[t] = v + a;
        __syncthreads();
    }
    int ex = loff[t] - cnt[t];  // exclusive
    cur[t] = ex;
    int node = node0 + t;
    if (node < N_NODES) {
        row_off[node] = base + ex;
        int d = cnt[t];
        inv_deg[node] = 1.0f / (float)(d > 1 ? d : 1);
    }
    if (b == 0 && t == 0) row_off[N_NODES] = N_EDGES;
    __syncthreads();
    for (int i = t; i < n; i += 256) {
        unsigned ev = eb[i];
        int p = atomicAdd(&cur[(ev >> 16) & 255], 1);
        stage[p] = (int)(ev & 0xFFFFu);
    }
    __syncthreads();
    for (int i = t; i < n; i += 256) srcs[base + i] = stage[i];
}

// ---------------- weight prep: Wcat = [Wl | Wr], bf16 hi/lo split ----------
// Also zeroes gcur for k_bucket (same stream, runs before it).

__global__ __launch_bounds__(256) void k_prep(
    const float* __restrict__ W2l, const float* __restrict__ W2r,
    const float* __restrict__ W3l, const float* __restrict__ W3r,
    unsigned short* __restrict__ W2hi, unsigned short* __restrict__ W2lo,
    unsigned short* __restrict__ W3hi, unsigned short* __restrict__ W3lo,
    int* __restrict__ gcur) {
    int t = blockIdx.x * 256 + threadIdx.x;
    int stride = gridDim.x * 256;
    if (blockIdx.x == 0 && threadIdx.x < NB) gcur[threadIdx.x] = 0;
    for (int p = t; p < 64 * 128; p += stride) {
        int j = p >> 7, k = p & 127;
        float w = (k < 64) ? W2l[j * 64 + k] : W2r[j * 64 + (k - 64)];
        unsigned short h = f2bf(w);
        W2hi[p] = h;
        W2lo[p] = f2bf(w - bf2f(h));
    }
    for (int p = t; p < 32 * 128; p += stride) {
        int j = p >> 7, k = p & 127;
        float w = (k < 64) ? W3l[j * 64 + k] : W3r[j * 64 + (k - 64)];
        unsigned short h = f2bf(w);
        W3hi[p] = h;
        W3lo[p] = f2bf(w - bf2f(h));
    }
}

// ---------------- Layer 1: 5 -> 64 fused matvec, ReLU, fp16 output ---------
// Wave per node; lane -> (neighbor slot l>>3, channel l&7): 8 neighbor rows
// per load instruction. Cross-slot reduce via 3 shfl_xor.

__global__ __launch_bounds__(512) void k_layer1(
    const float* __restrict__ x, const int* __restrict__ row_off,
    const int* __restrict__ srcs, const float* __restrict__ inv_deg,
    const float* __restrict__ W1l, const float* __restrict__ b1,
    const float* __restrict__ W1r, __half* __restrict__ h1) {
    const int t = threadIdx.x;
    const int lane = t & 63;
    const int v = blockIdx.x * 8 + (t >> 6);
    if (v >= N_NODES) return;
    const int sub = lane >> 3;  // neighbor slot 0..7
    const int c = lane & 7;     // channel, < IN_C valid

    float wl[IN_C], wr[IN_C];
#pragma unroll
    for (int i = 0; i < IN_C; ++i) {
        wl[i] = W1l[lane * IN_C + i];
        wr[i] = W1r[lane * IN_C + i];
    }
    float bb = b1[lane];

    int beg = rfl(row_off[v]);
    int end = rfl(row_off[v + 1]);
    float sum = 0.f;
    for (int e = beg; e < end; e += 8) {
        int o = e + sub;
        if (o < end && c < IN_C) sum += x[srcs[o] * IN_C + c];
    }
    sum += __shfl_xor(sum, 8, 64);
    sum += __shfl_xor(sum, 16, 64);
    sum += __shfl_xor(sum, 32, 64);
    float summ = sum * inv_deg[v];  // lane i (i<IN_C) holds channel i
    float xv = (lane < IN_C) ? x[v * IN_C + lane] : 0.f;
    float acc = bb;
#pragma unroll
    for (int i = 0; i < IN_C; ++i) {
        acc += wl[i] * lanebc(summ, i);
        acc += wr[i] * lanebc(xv, i);
    }
    h1[v * HID_C + lane] = __float2half(fmaxf(acc, 0.f));
}

// ---------------- fused gather + GEMM (layers 2/3) ----------------
// Block = 4 waves = 16 nodes. Gather: lane -> (neighbor slot l>>4, channel
// group l&15): one dwordx2 = 4 fp16 channels, 4 neighbor rows per wave
// instruction; fp32 accumulate; cross-slot reduce = 8 shfl_xor per node.
// Slot-0 lanes write mean, slot-1 lanes write root into the LDS A tile
// (bf16 hi/lo, padded stride -> 2-way banks = free). One barrier, then wave
// n (n < DOUT/16) computes output tile n with 12 MFMAs (3-product split).

template <typename T> __device__ __forceinline__ T cvt_out(float v);
template <> __device__ __forceinline__ float cvt_out<float>(float v) { return v; }
template <> __device__ __forceinline__ __half cvt_out<__half>(float v) { return __float2half(v); }

template <int DOUT, bool RELU, typename OutT>
__global__ __launch_bounds__(256) void k_fused(
    const __half* __restrict__ h, const int* __restrict__ row_off,
    const int* __restrict__ srcs, const float* __restrict__ inv_deg,
    const unsigned short* __restrict__ Whi, const unsigned short* __restrict__ Wlo,
    const float* __restrict__ bias, OutT* __restrict__ out) {
    constexpr int AP = 136;  // padded LDS row stride (ushorts)
    __shared__ __align__(16) unsigned short Ah[16][AP];
    __shared__ __align__(16) unsigned short Al[16][AP];
    const int t = threadIdx.x;
    const int lane = t & 63;
    const int w = t >> 6;
    const int sub = lane >> 4;  // neighbor slot 0..3
    const int cg = lane & 15;   // channel group (4 halves)
    const int node0 = blockIdx.x * 16;  // N_NODES = 3125*16 exactly
    const unsigned* h32 = (const unsigned*)h;  // row stride 32 uints

    for (int m = w * 4; m < w * 4 + 4; ++m) {
        const int v = node0 + m;
        int beg = rfl(row_off[v]);
        int end = rfl(row_off[v + 1]);
        float f0 = 0.f, f1 = 0.f, f2 = 0.f, f3 = 0.f;
        for (int e = beg; e < end; e += 8) {
            int o0 = e + sub;
            int o1 = e + 4 + sub;
            if (o0 < end) {
                uint2 u = *(const uint2*)(h32 + srcs[o0] * 32 + cg * 2);
                float2 p0 = unpk_h2(u.x), p1 = unpk_h2(u.y);
                f0 += p0.x; f1 += p0.y; f2 += p1.x; f3 += p1.y;
            }
            if (o1 < end) {
                uint2 u = *(const uint2*)(h32 + srcs[o1] * 32 + cg * 2);
                float2 p0 = unpk_h2(u.x), p1 = unpk_h2(u.y);
                f0 += p0.x; f1 += p0.y; f2 += p1.x; f3 += p1.y;
            }
        }
        f0 += __shfl_xor(f0, 16, 64); f1 += __shfl_xor(f1, 16, 64);
        f2 += __shfl_xor(f2, 16, 64); f3 += __shfl_xor(f3, 16, 64);
        f0 += __shfl_xor(f0, 32, 64); f1 += __shfl_xor(f1, 32, 64);
        f2 += __shfl_xor(f2, 32, 64); f3 += __shfl_xor(f3, 32, 64);

        float idg = inv_deg[v];
        if (sub == 0) {
            float m0 = f0 * idg, m1 = f1 * idg, m2 = f2 * idg, m3 = f3 * idg;
            unsigned short a0 = f2bf(m0), a1 = f2bf(m1), a2 = f2bf(m2), a3 = f2bf(m3);
            uint2 hi, lo;
            hi.x = (unsigned)a0 | ((unsigned)a1 << 16);
            hi.y = (unsigned)a2 | ((unsigned)a3 << 16);
            lo.x = (unsigned)f2bf(m0 - bf2f(a0)) | ((unsigned)f2bf(m1 - bf2f(a1)) << 16);
            lo.y = (unsigned)f2bf(m2 - bf2f(a2)) | ((unsigned)f2bf(m3 - bf2f(a3)) << 16);
            *(uint2*)&Ah[m][cg * 4] = hi;
            *(uint2*)&Al[m][cg * 4] = lo;
        } else if (sub == 1) {
            uint2 u = *(const uint2*)(h32 + v * 32 + cg * 2);
            float2 p0 = unpk_h2(u.x), p1 = unpk_h2(u.y);
            unsigned short a0 = f2bf(p0.x), a1 = f2bf(p0.y);
            unsigned short a2 = f2bf(p1.x), a3 = f2bf(p1.y);
            uint2 hi, lo;
            hi.x = (unsigned)a0 | ((unsigned)a1 << 16);
            hi.y = (unsigned)a2 | ((unsigned)a3 << 16);
            lo.x = (unsigned)f2bf(p0.x - bf2f(a0)) | ((unsigned)f2bf(p0.y - bf2f(a1)) << 16);
            lo.y = (unsigned)f2bf(p1.x - bf2f(a2)) | ((unsigned)f2bf(p1.y - bf2f(a3)) << 16);
            *(uint2*)&Ah[m][64 + cg * 4] = hi;
            *(uint2*)&Al[m][64 + cg * 4] = lo;
        }
    }
    __syncthreads();

    constexpr int NT = DOUT / 16;
    if (w < NT) {
        const int r = lane & 15;
        const int quad = lane >> 4;
        f32x4 acc = (f32x4){0.f, 0.f, 0.f, 0.f};
#pragma unroll
        for (int ks = 0; ks < 4; ++ks) {
            bf16x8 ah = *(const bf16x8*)&Ah[r][ks * 32 + quad * 8];
            bf16x8 al = *(const bf16x8*)&Al[r][ks * 32 + quad * 8];
            const size_t wb = ((size_t)(w * 16 + r)) * 128 + ks * 32 + quad * 8;
            bf16x8 bh = *(const bf16x8*)(Whi + wb);
            bf16x8 bl = *(const bf16x8*)(Wlo + wb);
            acc = __builtin_amdgcn_mfma_f32_16x16x32_bf16(ah, bh, acc, 0, 0, 0);
            acc = __builtin_amdgcn_mfma_f32_16x16x32_bf16(ah, bl, acc, 0, 0, 0);
            acc = __builtin_amdgcn_mfma_f32_16x16x32_bf16(al, bh, acc, 0, 0, 0);
        }
        float bv = bias[w * 16 + r];
#pragma unroll
        for (int g = 0; g < 4; ++g) {
            int m = quad * 4 + g;
            float vv = acc[g] + bv;
            if (RELU) vv = fmaxf(vv, 0.f);
            out[(size_t)(node0 + m) * DOUT + w * 16 + r] = cvt_out<OutT>(vv);
        }
    }
}

// ---------------- launch ----------------

extern "C" void kernel_launch(void* const* d_in, const int* in_sizes, int n_in,
                              void* d_out, int out_size, void* d_ws, size_t ws_size,
                              hipStream_t stream) {
    const float* x   = (const float*)d_in[0];
    const int*   ei  = (const int*)d_in[1];  // [2,E]: row0=src, row1=dst
    const float* W1l = (const float*)d_in[2];
    const float* b1  = (const float*)d_in[3];
    const float* W1r = (const float*)d_in[4];
    const float* W2l = (const float*)d_in[5];
    const float* b2  = (const float*)d_in[6];
    const float* W2r = (const float*)d_in[7];
    const float* W3l = (const float*)d_in[8];
    const float* b3  = (const float*)d_in[9];
    const float* W3r = (const float*)d_in[10];

    char* ws = (char*)d_ws;
    size_t off = 0;
    auto alloc = [&](size_t bytes) -> char* {
        char* p = ws + off;
        off += (bytes + 255) & ~(size_t)255;
        return p;
    };
    int*      gcur   = (int*)alloc(NB * sizeof(int));
    int*      rowoff = (int*)alloc((N_NODES + 1) * sizeof(int));
    float*    invdeg = (float*)alloc(N_NODES * sizeof(float));
    int*      srcs   = (int*)alloc(N_EDGES * sizeof(int));
    unsigned* ebuf   = (unsigned*)alloc((size_t)NB * BCAP * sizeof(unsigned));
    __half*   h1     = (__half*)alloc((size_t)N_NODES * HID_C * sizeof(__half));
    __half*   h2     = (__half*)alloc((size_t)N_NODES * HID_C * sizeof(__half));
    unsigned short* W2hi = (unsigned short*)alloc(64 * 128 * 2);
    unsigned short* W2lo = (unsigned short*)alloc(64 * 128 * 2);
    unsigned short* W3hi = (unsigned short*)alloc(32 * 128 * 2);
    unsigned short* W3lo = (unsigned short*)alloc(32 * 128 * 2);

    // CSR build (k_prep also zeroes gcur; same-stream ordering)
    k_prep<<<dim3(48), dim3(256), 0, stream>>>(W2l, W2r, W3l, W3r,
                                               W2hi, W2lo, W3hi, W3lo, gcur);
    k_bucket<<<dim3(BWG), dim3(256), 0, stream>>>(ei, gcur, ebuf);
    k_bsort<<<dim3(NB), dim3(256), 0, stream>>>(gcur, ebuf, rowoff, invdeg, srcs);

    // layer 1 (fused matvec): x -> h1 (fp16)
    k_layer1<<<dim3((N_NODES + 7) / 8), dim3(512), 0, stream>>>(
        x, rowoff, srcs, invdeg, W1l, b1, W1r, h1);

    // layer 2: fused gather+gemm, h1 -> h2 (fp16, ReLU)
    k_fused<HID_C, true, __half><<<dim3(N_NODES / 16), dim3(256), 0, stream>>>(
        h1, rowoff, srcs, invdeg, W2hi, W2lo, b2, h2);

    // layer 3: fused gather+gemm, h2 -> out (fp32)
    k_fused<OUT_C, false, float><<<dim3(N_NODES / 16), dim3(256), 0, stream>>>(
        h2, rowoff, srcs, invdeg, W3hi, W3lo, b3, (float*)d_out);
}

// Round 8
// 185.869 us; speedup vs baseline: 2.7325x; 1.1591x over previous
//
#include <hip/hip_runtime.h>
#include <hip/hip_fp16.h>

// GraphSAGE 3-layer (mean aggr): N=50000, E=800000, 5->64->64->32.
// Round 8: k_fused gather restructured to lockstep-4-nodes per wave:
// lane -> (node slot l>>4, channel group l&15); each lane accumulates its
// 4 channels over ALL its node's neighbors (no cross-lane reduce, zero
// shuffles), k-loop unrolled x4 for MLP. MFMA phase unchanged (16x16x32
// bf16, 3-product hi/lo split = fp32-grade). CSR via bucketed counting sort.

#define N_NODES 50000
#define N_EDGES 800000
#define IN_C 5
#define HID_C 64
#define OUT_C 32

#define NB 196        // buckets of 256 nodes (dst >> 8)
#define BCAP 6144     // per-bucket region capacity (mean 4082, sigma ~64)
#define BWG 256       // k_bucket workgroups
#define BCH (N_EDGES / BWG)  // 3125 edges per workgroup

typedef __attribute__((ext_vector_type(8))) short bf16x8;   // 8 bf16 = 4 VGPRs
typedef __attribute__((ext_vector_type(4))) float f32x4;    // 4 fp32 acc

__device__ __forceinline__ int rfl(int v) { return __builtin_amdgcn_readfirstlane(v); }
__device__ __forceinline__ float lanebc(float v, int l) {
    return __int_as_float(__builtin_amdgcn_readlane(__float_as_int(v), l));
}
__device__ __forceinline__ unsigned short f2bf(float f) {  // RNE
    unsigned u = __float_as_uint(f);
    return (unsigned short)((u + 0x7fffu + ((u >> 16) & 1u)) >> 16);
}
__device__ __forceinline__ float bf2f(unsigned short b) {
    return __uint_as_float(((unsigned)b) << 16);
}
__device__ __forceinline__ float2 unpk_h2(unsigned u) {
    __half2 h = *(__half2*)&u;
    return __half22float2(h);
}

// ---------------- CSR build ----------------

__global__ __launch_bounds__(256) void k_bucket(const int* __restrict__ ei,
                                                int* __restrict__ gcur,
                                                unsigned* __restrict__ ebuf) {
    __shared__ int hist[NB];
    __shared__ int loff[NB];
    __shared__ int cur[NB];
    __shared__ int gbase[NB];
    __shared__ int scanb[256];
    __shared__ unsigned stage[BCH];
    const int t = threadIdx.x;
    const int c0 = blockIdx.x * BCH;

    if (t < NB) hist[t] = 0;
    __syncthreads();
    for (int i = t; i < BCH; i += 256) {
        int d = ei[N_EDGES + c0 + i];
        atomicAdd(&hist[d >> 8], 1);
    }
    __syncthreads();
    scanb[t] = (t < NB) ? hist[t] : 0;
    __syncthreads();
#pragma unroll
    for (int o = 1; o < 256; o <<= 1) {
        int v = scanb[t];
        int a = (t >= o) ? scanb[t - o] : 0;
        __syncthreads();
        scanb[t] = v + a;
        __syncthreads();
    }
    if (t < NB) {
        int ex = (t == 0) ? 0 : scanb[t - 1];
        loff[t] = ex;
        cur[t] = ex;
        gbase[t] = atomicAdd(&gcur[t], hist[t]);
    }
    __syncthreads();
    for (int i = t; i < BCH; i += 256) {
        int d = ei[N_EDGES + c0 + i];
        int s = ei[c0 + i];
        int b = d >> 8;
        int p = atomicAdd(&cur[b], 1);
        stage[p] = ((unsigned)d << 16) | (unsigned)s;
    }
    __syncthreads();
    for (int i = t; i < BCH; i += 256) {
        unsigned ev = stage[i];
        int b = ev >> 24;
        int pos = gbase[b] + (i - loff[b]);
        if (pos < BCAP) ebuf[b * BCAP + pos] = ev;
    }
}

__global__ __launch_bounds__(256) void k_bsort(const int* __restrict__ gcur,
                                               const unsigned* __restrict__ ebuf,
                                               int* __restrict__ row_off,
                                               float* __restrict__ inv_deg,
                                               int* __restrict__ srcs) {
    __shared__ int sc[256];
    __shared__ int cnt[256];
    __shared__ int loff[256];
    __shared__ int cur[256];
    __shared__ int stage[BCAP];
    const int t = threadIdx.x;
    const int b = blockIdx.x;

    sc[t] = (t < NB) ? gcur[t] : 0;
    __syncthreads();
#pragma unroll
    for (int o = 1; o < 256; o <<= 1) {
        int v = sc[t];
        int a = (t >= o) ? sc[t - o] : 0;
        __syncthreads();
        sc[t] = v + a;
        __syncthreads();
    }
    const int base = (b == 0) ? 0 : sc[b - 1];
    const int nraw = gcur[b];
    const int n = nraw < BCAP ? nraw : BCAP;
    const int node0 = b << 8;
    const unsigned* eb = ebuf + b * BCAP;

    cnt[t] = 0;
    __syncthreads();
    for (int i = t; i < n; i += 256) atomicAdd(&cnt[(eb[i] >> 16) & 255], 1);
    __syncthreads();
    loff[t] = cnt[t];
    __syncthreads();
#pragma unroll
    for (int o = 1; o < 256; o <<= 1) {
        int v = loff[t];
        int a = (t >= o) ? loff[t - o] : 0;
        __syncthreads();
        loff[t] = v + a;
        __syncthreads();
    }
    int ex = loff[t] - cnt[t];  // exclusive
    cur[t] = ex;
    int node = node0 + t;
    if (node < N_NODES) {
        row_off[node] = base + ex;
        int d = cnt[t];
        inv_deg[node] = 1.0f / (float)(d > 1 ? d : 1);
    }
    if (b == 0 && t == 0) row_off[N_NODES] = N_EDGES;
    __syncthreads();
    for (int i = t; i < n; i += 256) {
        unsigned ev = eb[i];
        int p = atomicAdd(&cur[(ev >> 16) & 255], 1);
        stage[p] = (int)(ev & 0xFFFFu);
    }
    __syncthreads();
    for (int i = t; i < n; i += 256) srcs[base + i] = stage[i];
}

// ---------------- weight prep: Wcat = [Wl | Wr], bf16 hi/lo split ----------

__global__ __launch_bounds__(256) void k_prep(
    const float* __restrict__ W2l, const float* __restrict__ W2r,
    const float* __restrict__ W3l, const float* __restrict__ W3r,
    unsigned short* __restrict__ W2hi, unsigned short* __restrict__ W2lo,
    unsigned short* __restrict__ W3hi, unsigned short* __restrict__ W3lo,
    int* __restrict__ gcur) {
    int t = blockIdx.x * 256 + threadIdx.x;
    int stride = gridDim.x * 256;
    if (blockIdx.x == 0 && threadIdx.x < NB) gcur[threadIdx.x] = 0;
    for (int p = t; p < 64 * 128; p += stride) {
        int j = p >> 7, k = p & 127;
        float w = (k < 64) ? W2l[j * 64 + k] : W2r[j * 64 + (k - 64)];
        unsigned short h = f2bf(w);
        W2hi[p] = h;
        W2lo[p] = f2bf(w - bf2f(h));
    }
    for (int p = t; p < 32 * 128; p += stride) {
        int j = p >> 7, k = p & 127;
        float w = (k < 64) ? W3l[j * 64 + k] : W3r[j * 64 + (k - 64)];
        unsigned short h = f2bf(w);
        W3hi[p] = h;
        W3lo[p] = f2bf(w - bf2f(h));
    }
}

// ---------------- Layer 1: 5 -> 64 fused matvec, ReLU, fp16 output ---------

__global__ __launch_bounds__(512) void k_layer1(
    const float* __restrict__ x, const int* __restrict__ row_off,
    const int* __restrict__ srcs, const float* __restrict__ inv_deg,
    const float* __restrict__ W1l, const float* __restrict__ b1,
    const float* __restrict__ W1r, __half* __restrict__ h1) {
    const int t = threadIdx.x;
    const int lane = t & 63;
    const int v = blockIdx.x * 8 + (t >> 6);
    if (v >= N_NODES) return;
    const int sub = lane >> 3;  // neighbor slot 0..7
    const int c = lane & 7;     // channel, < IN_C valid

    float wl[IN_C], wr[IN_C];
#pragma unroll
    for (int i = 0; i < IN_C; ++i) {
        wl[i] = W1l[lane * IN_C + i];
        wr[i] = W1r[lane * IN_C + i];
    }
    float bb = b1[lane];

    int beg = rfl(row_off[v]);
    int end = rfl(row_off[v + 1]);
    float sum = 0.f;
    for (int e = beg; e < end; e += 8) {
        int o = e + sub;
        if (o < end && c < IN_C) sum += x[srcs[o] * IN_C + c];
    }
    sum += __shfl_xor(sum, 8, 64);
    sum += __shfl_xor(sum, 16, 64);
    sum += __shfl_xor(sum, 32, 64);
    float summ = sum * inv_deg[v];  // lane i (i<IN_C) holds channel i
    float xv = (lane < IN_C) ? x[v * IN_C + lane] : 0.f;
    float acc = bb;
#pragma unroll
    for (int i = 0; i < IN_C; ++i) {
        acc += wl[i] * lanebc(summ, i);
        acc += wr[i] * lanebc(xv, i);
    }
    h1[v * HID_C + lane] = __float2half(fmaxf(acc, 0.f));
}

// ---------------- fused gather + GEMM (layers 2/3) ----------------
// Block = 4 waves = 16 nodes. Gather: lane -> (node slot ns=l>>4, channel
// group cg=l&15). Each wave advances its 4 nodes in lockstep: per k, lane
// loads uint2 (4 fp16 ch) of neighbor k of node ns; after the loop the lane
// holds the complete 4-channel sum for its node (NO cross-lane reduce).
// k-loop unrolled x4 (4 srcs + 4 row loads in flight). Every lane writes its
// node's mean+root quarters (bf16 hi/lo) to the LDS A tile; one barrier;
// wave n (n < DOUT/16) computes output tile n with 12 MFMAs.

template <typename T> __device__ __forceinline__ T cvt_out(float v);
template <> __device__ __forceinline__ float cvt_out<float>(float v) { return v; }
template <> __device__ __forceinline__ __half cvt_out<__half>(float v) { return __float2half(v); }

template <int DOUT, bool RELU, typename OutT>
__global__ __launch_bounds__(256) void k_fused(
    const __half* __restrict__ h, const int* __restrict__ row_off,
    const int* __restrict__ srcs, const float* __restrict__ inv_deg,
    const unsigned short* __restrict__ Whi, const unsigned short* __restrict__ Wlo,
    const float* __restrict__ bias, OutT* __restrict__ out) {
    constexpr int AP = 136;  // padded LDS row stride (ushorts)
    __shared__ __align__(16) unsigned short Ah[16][AP];
    __shared__ __align__(16) unsigned short Al[16][AP];
    const int t = threadIdx.x;
    const int lane = t & 63;
    const int w = t >> 6;
    const int ns = lane >> 4;   // node slot 0..3
    const int cg = lane & 15;   // channel group (4 halves)
    const int node0 = blockIdx.x * 16;  // N_NODES = 3125*16 exactly
    const unsigned* h32 = (const unsigned*)h;  // row stride 32 uints

    const int m = w * 4 + ns;       // block-local node 0..15
    const int v = node0 + m;
    const int beg = row_off[v];
    const int deg = row_off[v + 1] - beg;
    const unsigned* rowb = h32 + cg * 2;

    float f0 = 0.f, f1 = 0.f, f2 = 0.f, f3 = 0.f;
    for (int k = 0; k < deg; k += 4) {
        int i0 = srcs[beg + k];
        int i1 = (k + 1 < deg) ? srcs[beg + k + 1] : i0;
        int i2 = (k + 2 < deg) ? srcs[beg + k + 2] : i0;
        int i3 = (k + 3 < deg) ? srcs[beg + k + 3] : i0;
        uint2 u0 = *(const uint2*)(rowb + i0 * 32);
        uint2 u1 = *(const uint2*)(rowb + i1 * 32);
        uint2 u2 = *(const uint2*)(rowb + i2 * 32);
        uint2 u3 = *(const uint2*)(rowb + i3 * 32);
        float2 a0 = unpk_h2(u0.x), b0 = unpk_h2(u0.y);
        f0 += a0.x; f1 += a0.y; f2 += b0.x; f3 += b0.y;
        if (k + 1 < deg) {
            float2 a = unpk_h2(u1.x), b = unpk_h2(u1.y);
            f0 += a.x; f1 += a.y; f2 += b.x; f3 += b.y;
        }
        if (k + 2 < deg) {
            float2 a = unpk_h2(u2.x), b = unpk_h2(u2.y);
            f0 += a.x; f1 += a.y; f2 += b.x; f3 += b.y;
        }
        if (k + 3 < deg) {
            float2 a = unpk_h2(u3.x), b = unpk_h2(u3.y);
            f0 += a.x; f1 += a.y; f2 += b.x; f3 += b.y;
        }
    }

    // root row (4 channels for this lane)
    uint2 ur = *(const uint2*)(rowb + v * 32);
    float2 r0 = unpk_h2(ur.x), r1 = unpk_h2(ur.y);
    float idg = inv_deg[v];
    float m0 = f0 * idg, m1 = f1 * idg, m2 = f2 * idg, m3 = f3 * idg;

    {   // mean quarter -> LDS (bf16 hi/lo)
        unsigned short a0 = f2bf(m0), a1 = f2bf(m1), a2 = f2bf(m2), a3 = f2bf(m3);
        uint2 hi, lo;
        hi.x = (unsigned)a0 | ((unsigned)a1 << 16);
        hi.y = (unsigned)a2 | ((unsigned)a3 << 16);
        lo.x = (unsigned)f2bf(m0 - bf2f(a0)) | ((unsigned)f2bf(m1 - bf2f(a1)) << 16);
        lo.y = (unsigned)f2bf(m2 - bf2f(a2)) | ((unsigned)f2bf(m3 - bf2f(a3)) << 16);
        *(uint2*)&Ah[m][cg * 4] = hi;
        *(uint2*)&Al[m][cg * 4] = lo;
    }
    {   // root quarter -> LDS
        unsigned short a0 = f2bf(r0.x), a1 = f2bf(r0.y), a2 = f2bf(r1.x), a3 = f2bf(r1.y);
        uint2 hi, lo;
        hi.x = (unsigned)a0 | ((unsigned)a1 << 16);
        hi.y = (unsigned)a2 | ((unsigned)a3 << 16);
        lo.x = (unsigned)f2bf(r0.x - bf2f(a0)) | ((unsigned)f2bf(r0.y - bf2f(a1)) << 16);
        lo.y = (unsigned)f2bf(r1.x - bf2f(a2)) | ((unsigned)f2bf(r1.y - bf2f(a3)) << 16);
        *(uint2*)&Ah[m][64 + cg * 4] = hi;
        *(uint2*)&Al[m][64 + cg * 4] = lo;
    }
    __syncthreads();

    constexpr int NT = DOUT / 16;
    if (w < NT) {
        const int r = lane & 15;
        const int quad = lane >> 4;
        f32x4 acc = (f32x4){0.f, 0.f, 0.f, 0.f};
#pragma unroll
        for (int ks = 0; ks < 4; ++ks) {
            bf16x8 ah = *(const bf16x8*)&Ah[r][ks * 32 + quad * 8];
            bf16x8 al = *(const bf16x8*)&Al[r][ks * 32 + quad * 8];
            const size_t wb = ((size_t)(w * 16 + r)) * 128 + ks * 32 + quad * 8;
            bf16x8 bh = *(const bf16x8*)(Whi + wb);
            bf16x8 bl = *(const bf16x8*)(Wlo + wb);
            acc = __builtin_amdgcn_mfma_f32_16x16x32_bf16(ah, bh, acc, 0, 0, 0);
            acc = __builtin_amdgcn_mfma_f32_16x16x32_bf16(ah, bl, acc, 0, 0, 0);
            acc = __builtin_amdgcn_mfma_f32_16x16x32_bf16(al, bh, acc, 0, 0, 0);
        }
        float bv = bias[w * 16 + r];
#pragma unroll
        for (int g = 0; g < 4; ++g) {
            int mm = quad * 4 + g;
            float vv = acc[g] + bv;
            if (RELU) vv = fmaxf(vv, 0.f);
            out[(size_t)(node0 + mm) * DOUT + w * 16 + r] = cvt_out<OutT>(vv);
        }
    }
}

// ---------------- launch ----------------

extern "C" void kernel_launch(void* const* d_in, const int* in_sizes, int n_in,
                              void* d_out, int out_size, void* d_ws, size_t ws_size,
                              hipStream_t stream) {
    const float* x   = (const float*)d_in[0];
    const int*   ei  = (const int*)d_in[1];  // [2,E]: row0=src, row1=dst
    const float* W1l = (const float*)d_in[2];
    const float* b1  = (const float*)d_in[3];
    const float* W1r = (const float*)d_in[4];
    const float* W2l = (const float*)d_in[5];
    const float* b2  = (const float*)d_in[6];
    const float* W2r = (const float*)d_in[7];
    const float* W3l = (const float*)d_in[8];
    const float* b3  = (const float*)d_in[9];
    const float* W3r = (const float*)d_in[10];

    char* ws = (char*)d_ws;
    size_t off = 0;
    auto alloc = [&](size_t bytes) -> char* {
        char* p = ws + off;
        off += (bytes + 255) & ~(size_t)255;
        return p;
    };
    int*      gcur   = (int*)alloc(NB * sizeof(int));
    int*      rowoff = (int*)alloc((N_NODES + 1) * sizeof(int));
    float*    invdeg = (float*)alloc(N_NODES * sizeof(float));
    int*      srcs   = (int*)alloc(N_EDGES * sizeof(int));
    unsigned* ebuf   = (unsigned*)alloc((size_t)NB * BCAP * sizeof(unsigned));
    __half*   h1     = (__half*)alloc((size_t)N_NODES * HID_C * sizeof(__half));
    __half*   h2     = (__half*)alloc((size_t)N_NODES * HID_C * sizeof(__half));
    unsigned short* W2hi = (unsigned short*)alloc(64 * 128 * 2);
    unsigned short* W2lo = (unsigned short*)alloc(64 * 128 * 2);
    unsigned short* W3hi = (unsigned short*)alloc(32 * 128 * 2);
    unsigned short* W3lo = (unsigned short*)alloc(32 * 128 * 2);

    // CSR build (k_prep also zeroes gcur; same-stream ordering)
    k_prep<<<dim3(48), dim3(256), 0, stream>>>(W2l, W2r, W3l, W3r,
                                               W2hi, W2lo, W3hi, W3lo, gcur);
    k_bucket<<<dim3(BWG), dim3(256), 0, stream>>>(ei, gcur, ebuf);
    k_bsort<<<dim3(NB), dim3(256), 0, stream>>>(gcur, ebuf, rowoff, invdeg, srcs);

    // layer 1 (fused matvec): x -> h1 (fp16)
    k_layer1<<<dim3((N_NODES + 7) / 8), dim3(512), 0, stream>>>(
        x, rowoff, srcs, invdeg, W1l, b1, W1r, h1);

    // layer 2: fused gather+gemm, h1 -> h2 (fp16, ReLU)
    k_fused<HID_C, true, __half><<<dim3(N_NODES / 16), dim3(256), 0, stream>>>(
        h1, rowoff, srcs, invdeg, W2hi, W2lo, b2, h2);

    // layer 3: fused gather+gemm, h2 -> out (fp32)
    k_fused<OUT_C, false, float><<<dim3(N_NODES / 16), dim3(256), 0, stream>>>(
        h2, rowoff, srcs, invdeg, W3hi, W3lo, b3, (float*)d_out);
}